// Round 1
// baseline (9762.564 us; speedup 1.0000x reference)
//
#include <hip/hip_runtime.h>

typedef unsigned int u32;
typedef unsigned short u16;
typedef unsigned long long u64;
typedef _Float16 f16;
typedef f16 f16x2 __attribute__((ext_vector_type(2)));

__device__ __forceinline__ float fdot2(u32 a, u32 b, float c) {
#if __has_builtin(__builtin_amdgcn_fdot2)
    return __builtin_amdgcn_fdot2(__builtin_bit_cast(f16x2, a),
                                  __builtin_bit_cast(f16x2, b), c, false);
#else
    f16x2 av = __builtin_bit_cast(f16x2, a), bv = __builtin_bit_cast(f16x2, b);
    c += (float)av[0] * (float)bv[0];
    c += (float)av[1] * (float)bv[1];
    return c;
#endif
}

__device__ __forceinline__ u32 pack2h(float a, float b) {
    f16x2 h; h[0] = (f16)a; h[1] = (f16)b;
    return __builtin_bit_cast(u32, h);
}
__device__ __forceinline__ float h2f(u16 x) { return (float)__builtin_bit_cast(f16, x); }
__device__ __forceinline__ u16 f2h(float x) { f16 h = (f16)x; return __builtin_bit_cast(u16, h); }

__device__ __forceinline__ float fexp(float x) {
#if __has_builtin(__builtin_amdgcn_exp2f)
    return __builtin_amdgcn_exp2f(x * 1.44269504088896f);
#else
    return __expf(x);
#endif
}
__device__ __forceinline__ float frcp(float x) {
#if __has_builtin(__builtin_amdgcn_rcpf)
    return __builtin_amdgcn_rcpf(x);
#else
    return 1.0f / x;
#endif
}
__device__ __forceinline__ float fsigmoid(float x) { return frcp(1.0f + fexp(-x)); }
__device__ __forceinline__ float ftanh_pos(float x) { return 1.0f - 2.0f * frcp(fexp(2.0f * x) + 1.0f); }

// ---------------------------------------------------------------------------
// K0: pack weights to f16 pairs. (unchanged)
//   WpkT[d][p] = (Wi[d][2p], Wi[d][2p+1])   d<512, p<256   (row-major rows)
//   Wypk[p][d] = (Wy[d][2p], Wy[d][2p+1])   (K2 epilogue layout)
// ---------------------------------------------------------------------------
__global__ __launch_bounds__(256) void k0_pack(const float* __restrict__ Wi,
                                               const float* __restrict__ Wy,
                                               u32* __restrict__ WpkT,
                                               u32* __restrict__ Wypk) {
    const int bx = blockIdx.x, tid = threadIdx.x;
    if (bx < 512) {
        const float2 v = *(const float2*)(Wi + (size_t)bx * 512 + 2 * tid);
        WpkT[(size_t)bx * 256 + tid] = pack2h(v.x, v.y);
    } else {
        const int p = bx - 512;
        #pragma unroll
        for (int r = 0; r < 2; ++r) {
            const int d = tid + 256 * r;
            Wypk[(size_t)p * 512 + d] =
                pack2h(Wy[(size_t)d * 512 + 2 * p], Wy[(size_t)d * 512 + 2 * p + 1]);
        }
    }
}

// ---------------------------------------------------------------------------
// K1: gate pre-activations (parallel over all t). Unchanged.
// ---------------------------------------------------------------------------
__global__ __launch_bounds__(256) void k1_gates(
    const float* __restrict__ word,
    const float* __restrict__ Wi, const float* __restrict__ Wz, const float* __restrict__ Wo,
    const float* __restrict__ bi, const float* __restrict__ bz, const float* __restrict__ bo,
    u16* __restrict__ Xi, u16* __restrict__ Xz, u16* __restrict__ Xo)
{
    __shared__ uint4 ws2v[3][128][4];
    __shared__ u32 xs2[2][16][36];

    const int tid = threadIdx.x;
    const int d_l = tid & 63;
    const int bq  = tid >> 6;
    const int t0  = blockIdx.x * 2;
    const int d0  = blockIdx.y * 128;

    const float* Wg[3] = {Wi, Wz, Wo};

    float acc[2][2][8][3];
    #pragma unroll
    for (int tt = 0; tt < 2; ++tt)
        #pragma unroll
        for (int db = 0; db < 2; ++db)
            #pragma unroll
            for (int j = 0; j < 8; ++j)
                #pragma unroll
                for (int g = 0; g < 3; ++g) acc[tt][db][j][g] = 0.0f;

    for (int k0c = 0; k0c < 512; k0c += 32) {
        {
            const int p = tid & 15, bg = tid >> 4;
            #pragma unroll
            for (int tt = 0; tt < 2; ++tt)
                #pragma unroll
                for (int j = 0; j < 2; ++j) {
                    const int bb = bg * 2 + j;
                    const float2 v = *(const float2*)(word + (((size_t)(t0 + tt) * 32 + bb) * 512 + k0c + 2 * p));
                    xs2[tt][p][bb] = pack2h(v.x, v.y);
                }
        }
        {
            #pragma unroll
            for (int cc = 0; cc < 6; ++cc) {
                const int c = tid + 256 * cc;
                const int g = c >> 9, r = c & 511, pg = r >> 7, i = r & 127;
                const float* src = Wg[g] + (size_t)(d0 + i) * 512 + k0c + 8 * pg;
                const float4 v0 = ((const float4*)src)[0];
                const float4 v1 = ((const float4*)src)[1];
                uint4 cell;
                cell.x = pack2h(v0.x, v0.y); cell.y = pack2h(v0.z, v0.w);
                cell.z = pack2h(v1.x, v1.y); cell.w = pack2h(v1.z, v1.w);
                ws2v[g][i][(pg + (i >> 2)) & 3] = cell;
            }
        }
        __syncthreads();
        #pragma unroll
        for (int pg = 0; pg < 4; ++pg) {
            uint4 wc[3][2];
            #pragma unroll
            for (int g = 0; g < 3; ++g)
                #pragma unroll
                for (int db = 0; db < 2; ++db) {
                    const int d = d_l + 64 * db;
                    wc[g][db] = ws2v[g][d][(pg + (d >> 2)) & 3];
                }
            #pragma unroll
            for (int p = 0; p < 4; ++p) {
                const int pair = 4 * pg + p;
                u32 x2[2][8];
                #pragma unroll
                for (int tt = 0; tt < 2; ++tt) {
                    const uint4* xr = (const uint4*)&xs2[tt][pair][bq * 8];
                    uint4 xa = xr[0], xb = xr[1];
                    x2[tt][0] = xa.x; x2[tt][1] = xa.y; x2[tt][2] = xa.z; x2[tt][3] = xa.w;
                    x2[tt][4] = xb.x; x2[tt][5] = xb.y; x2[tt][6] = xb.z; x2[tt][7] = xb.w;
                }
                u32 w[3][2];
                #pragma unroll
                for (int g = 0; g < 3; ++g)
                    #pragma unroll
                    for (int db = 0; db < 2; ++db) {
                        const uint4 v = wc[g][db];
                        w[g][db] = (p == 0) ? v.x : (p == 1) ? v.y : (p == 2) ? v.z : v.w;
                    }
                #pragma unroll
                for (int tt = 0; tt < 2; ++tt)
                    #pragma unroll
                    for (int db = 0; db < 2; ++db)
                        #pragma unroll
                        for (int j = 0; j < 8; ++j)
                            #pragma unroll
                            for (int g = 0; g < 3; ++g)
                                acc[tt][db][j][g] = fdot2(x2[tt][j], w[g][db], acc[tt][db][j][g]);
            }
        }
        __syncthreads();
    }

    #pragma unroll
    for (int db = 0; db < 2; ++db) {
        const int d = d0 + 64 * db + d_l;
        const float b0 = 2.0f * bi[d];
        const float b1 = bz[d] + bi[d];
        const float b2 = bo[d] + bi[d];
        #pragma unroll
        for (int tt = 0; tt < 2; ++tt)
            #pragma unroll
            for (int j = 0; j < 8; ++j) {
                const size_t o = ((size_t)(t0 + tt) * 32 + (bq * 8 + j)) * 512 + d;
                Xi[o] = f2h(acc[tt][db][j][0] + b0);
                Xz[o] = f2h(acc[tt][db][j][1] + b1);
                Xo[o] = f2h(acc[tt][db][j][2] + b2);
            }
    }
}

// ---------------------------------------------------------------------------
// K2 v5: single-WG K-split recurrence. One 1024-thread WG per batch element.
// Thread tid -> (khalf = tid>>9, d = tid&511). Each thread computes the
// partial dot for output d over its K-half (128 f16-pairs held in 128 pinned
// VGPRs). Partner exchange is now an LDS write + __syncthreads + LDS read
// (tens of cycles) instead of the previous cross-WG L2/IC polling protocol
// (~3000 cy/step, 525 MB of HBM protocol writes). Gate math + h-publish run
// only on the half-0 waves; arithmetic order is bit-identical to v4:
// v = p_own(pairs 0..127) + p_partner(pairs 128..255), same accumulator
// interleave, same epilogue.
// ---------------------------------------------------------------------------
__global__ __launch_bounds__(1024, 1) void k2_recur(
    const u16* __restrict__ Xi, const u16* __restrict__ Xz, const u16* __restrict__ Xo,
    const u32* __restrict__ WpkT, const u32* __restrict__ Wypk,
    const float* __restrict__ by, float* __restrict__ out)
{
    __shared__ alignas(16) u16 hb[2][512];   // full h, f16, ping-pong
    __shared__ float pbuf[512];              // half-1 partial sums

    const int b    = blockIdx.x;             // 0..31
    const int tid  = threadIdx.x;
    const int half = tid >> 9;               // K-half (wave-uniform)
    const int d    = tid & 511;              // output dim

    // weight slice: output d, K-pairs [128*half, 128*half+128)
    const uint4* WpkT4 = (const uint4*)WpkT;
    u32 wq[128];
    #pragma unroll
    for (int i = 0; i < 32; ++i) {
        const uint4 v = WpkT4[(size_t)d * 64 + half * 32 + i];
        wq[4 * i + 0] = v.x; wq[4 * i + 1] = v.y;
        wq[4 * i + 2] = v.z; wq[4 * i + 3] = v.w;
    }
    #pragma unroll
    for (int i = 0; i < 128; ++i) asm volatile("" : "+v"(wq[i]));  // pin in regs

    if (tid < 512) hb[0][tid] = (u16)0;      // h = 0 at t = 0
    __syncthreads();

    u16 xi_c = 0, xz_c = 0, xo_c = 0;
    if (half == 0) {
        xi_c = Xi[(size_t)b * 512 + d];
        xz_c = Xz[(size_t)b * 512 + d];
        xo_c = Xo[(size_t)b * 512 + d];
    }

    float hn = 0.0f;
    for (int t = 0; t < 2048; ++t) {
        const int par = t & 1;

        // prefetch next-step x (half-0 only; latency hides under the dot)
        u16 xi_n = 0, xz_n = 0, xo_n = 0;
        if (half == 0) {
            const int tn = (t + 1) & 2047;
            const size_t xb = ((size_t)tn * 32 + b) * 512 + d;
            xi_n = Xi[xb]; xz_n = Xz[xb]; xo_n = Xo[xb];
        }

        // partial dot over own K-half (h broadcast from LDS, weights in regs)
        const uint4* hv = (const uint4*)&hb[par][half << 8];
        float a0 = 0.f, a1 = 0.f, a2 = 0.f, a3 = 0.f;
        #pragma unroll
        for (int i = 0; i < 32; ++i) {
            const uint4 hc = hv[i];
            a0 = fdot2(hc.x, wq[4 * i + 0], a0);
            a1 = fdot2(hc.y, wq[4 * i + 1], a1);
            a2 = fdot2(hc.z, wq[4 * i + 2], a2);
            a3 = fdot2(hc.w, wq[4 * i + 3], a3);
        }
        const float p = (a0 + a1) + (a2 + a3);

        if (half) pbuf[d] = p;               // half-1 posts its partial
        __syncthreads();                     // barrier A: partials visible
        if (!half) {
            const float v  = p + pbuf[d];    // same order as v4: own + partner
            const float zi = fsigmoid(h2f(xi_c) + v);
            const float z  = fsigmoid(h2f(xz_c) + v);
            const float zo = fsigmoid(h2f(xo_c) + v);
            hn = zo * ftanh_pos(zi * z);
            hb[par ^ 1][d] = f2h(hn);        // publish h for step t+1
        }
        __syncthreads();                     // barrier B: h visible

        xi_c = xi_n; xz_c = xz_n; xo_c = xo_n;
    }

    // epilogue: final h is in hb[0] (t=2047, par=1 wrote hb[0]).
    // Same arithmetic order as v4's epilogue; half-0 threads only.
    if (half == 0) {
        const uint4* hv = (const uint4*)&hb[0][0];
        float e0 = 0.f, e1 = 0.f, e2 = 0.f, e3 = 0.f;
        #pragma unroll 8
        for (int i = 0; i < 64; ++i) {
            const uint4 hc = hv[i];
            e0 = fdot2(hc.x, Wypk[(size_t)(4 * i + 0) * 512 + d], e0);
            e1 = fdot2(hc.y, Wypk[(size_t)(4 * i + 1) * 512 + d], e1);
            e2 = fdot2(hc.z, Wypk[(size_t)(4 * i + 2) * 512 + d], e2);
            e3 = fdot2(hc.w, Wypk[(size_t)(4 * i + 3) * 512 + d], e3);
        }
        out[(size_t)b * 512 + d] = (e0 + e1) + (e2 + e3) + by[d];
    }
}

// ---------------------------------------------------------------------------
extern "C" void kernel_launch(void* const* d_in, const int* in_sizes, int n_in,
                              void* d_out, int out_size, void* d_ws, size_t ws_size,
                              hipStream_t stream) {
    const float* word = (const float*)d_in[0];
    // d_in[1]=Wf, d_in[2]=bf : dead in the reference (c==0 path), unused.
    const float* Wi = (const float*)d_in[3];
    const float* bi = (const float*)d_in[4];
    const float* Wz = (const float*)d_in[5];
    const float* bz = (const float*)d_in[6];
    const float* Wo = (const float*)d_in[7];
    const float* bo = (const float*)d_in[8];
    const float* Wy = (const float*)d_in[9];
    const float* by = (const float*)d_in[10];
    float* out = (float*)d_out;

    char* ws = (char*)d_ws;
    const size_t XN = (size_t)2048 * 32 * 512 * sizeof(u16);  // 64 MB per gate array
    u16* Xi = (u16*)(ws);
    u16* Xz = (u16*)(ws + XN);
    u16* Xo = (u16*)(ws + 2 * XN);
    u32* WpkT = (u32*)(ws + 3 * XN);                          // 512 KB
    u32* Wypk = (u32*)(ws + 3 * XN + (size_t)524288);         // 512 KB

    k0_pack<<<768, 256, 0, stream>>>(Wi, Wy, WpkT, Wypk);

    dim3 g1(1024, 4);
    k1_gates<<<g1, 256, 0, stream>>>(word, Wi, Wz, Wo, bi, bz, bo, Xi, Xz, Xo);

    k2_recur<<<32, 1024, 0, stream>>>(Xi, Xz, Xo, WpkT, Wypk, by, out);
}

// Round 2
// 8710.043 us; speedup vs baseline: 1.1208x; 1.1208x over previous
//
#include <hip/hip_runtime.h>

typedef unsigned int u32;
typedef unsigned short u16;
typedef unsigned long long u64;
typedef _Float16 f16;
typedef f16 f16x2 __attribute__((ext_vector_type(2)));
typedef u32 u32x16 __attribute__((ext_vector_type(16)));

__device__ __forceinline__ float fdot2(u32 a, u32 b, float c) {
#if __has_builtin(__builtin_amdgcn_fdot2)
    return __builtin_amdgcn_fdot2(__builtin_bit_cast(f16x2, a),
                                  __builtin_bit_cast(f16x2, b), c, false);
#else
    f16x2 av = __builtin_bit_cast(f16x2, a), bv = __builtin_bit_cast(f16x2, b);
    c += (float)av[0] * (float)bv[0];
    c += (float)av[1] * (float)bv[1];
    return c;
#endif
}

__device__ __forceinline__ u32 pack2h(float a, float b) {
    f16x2 h; h[0] = (f16)a; h[1] = (f16)b;
    return __builtin_bit_cast(u32, h);
}
__device__ __forceinline__ float h2f(u16 x) { return (float)__builtin_bit_cast(f16, x); }
__device__ __forceinline__ u16 f2h(float x) { f16 h = (f16)x; return __builtin_bit_cast(u16, h); }

__device__ __forceinline__ float fexp(float x) {
#if __has_builtin(__builtin_amdgcn_exp2f)
    return __builtin_amdgcn_exp2f(x * 1.44269504088896f);
#else
    return __expf(x);
#endif
}
__device__ __forceinline__ float frcp(float x) {
#if __has_builtin(__builtin_amdgcn_rcpf)
    return __builtin_amdgcn_rcpf(x);
#else
    return 1.0f / x;
#endif
}
__device__ __forceinline__ float fsigmoid(float x) { return frcp(1.0f + fexp(-x)); }
__device__ __forceinline__ float ftanh_pos(float x) { return 1.0f - 2.0f * frcp(fexp(2.0f * x) + 1.0f); }

// ---------------------------------------------------------------------------
// K0: pack weights to f16 pairs. (unchanged)
//   WpkT[d][p] = (Wi[d][2p], Wi[d][2p+1])   d<512, p<256   (row-major rows)
//   Wypk[p][d] = (Wy[d][2p], Wy[d][2p+1])   (K2 epilogue layout)
// ---------------------------------------------------------------------------
__global__ __launch_bounds__(256) void k0_pack(const float* __restrict__ Wi,
                                               const float* __restrict__ Wy,
                                               u32* __restrict__ WpkT,
                                               u32* __restrict__ Wypk) {
    const int bx = blockIdx.x, tid = threadIdx.x;
    if (bx < 512) {
        const float2 v = *(const float2*)(Wi + (size_t)bx * 512 + 2 * tid);
        WpkT[(size_t)bx * 256 + tid] = pack2h(v.x, v.y);
    } else {
        const int p = bx - 512;
        #pragma unroll
        for (int r = 0; r < 2; ++r) {
            const int d = tid + 256 * r;
            Wypk[(size_t)p * 512 + d] =
                pack2h(Wy[(size_t)d * 512 + 2 * p], Wy[(size_t)d * 512 + 2 * p + 1]);
        }
    }
}

// ---------------------------------------------------------------------------
// K1: gate pre-activations (parallel over all t). Unchanged.
// ---------------------------------------------------------------------------
__global__ __launch_bounds__(256) void k1_gates(
    const float* __restrict__ word,
    const float* __restrict__ Wi, const float* __restrict__ Wz, const float* __restrict__ Wo,
    const float* __restrict__ bi, const float* __restrict__ bz, const float* __restrict__ bo,
    u16* __restrict__ Xi, u16* __restrict__ Xz, u16* __restrict__ Xo)
{
    __shared__ uint4 ws2v[3][128][4];
    __shared__ u32 xs2[2][16][36];

    const int tid = threadIdx.x;
    const int d_l = tid & 63;
    const int bq  = tid >> 6;
    const int t0  = blockIdx.x * 2;
    const int d0  = blockIdx.y * 128;

    const float* Wg[3] = {Wi, Wz, Wo};

    float acc[2][2][8][3];
    #pragma unroll
    for (int tt = 0; tt < 2; ++tt)
        #pragma unroll
        for (int db = 0; db < 2; ++db)
            #pragma unroll
            for (int j = 0; j < 8; ++j)
                #pragma unroll
                for (int g = 0; g < 3; ++g) acc[tt][db][j][g] = 0.0f;

    for (int k0c = 0; k0c < 512; k0c += 32) {
        {
            const int p = tid & 15, bg = tid >> 4;
            #pragma unroll
            for (int tt = 0; tt < 2; ++tt)
                #pragma unroll
                for (int j = 0; j < 2; ++j) {
                    const int bb = bg * 2 + j;
                    const float2 v = *(const float2*)(word + (((size_t)(t0 + tt) * 32 + bb) * 512 + k0c + 2 * p));
                    xs2[tt][p][bb] = pack2h(v.x, v.y);
                }
        }
        {
            #pragma unroll
            for (int cc = 0; cc < 6; ++cc) {
                const int c = tid + 256 * cc;
                const int g = c >> 9, r = c & 511, pg = r >> 7, i = r & 127;
                const float* src = Wg[g] + (size_t)(d0 + i) * 512 + k0c + 8 * pg;
                const float4 v0 = ((const float4*)src)[0];
                const float4 v1 = ((const float4*)src)[1];
                uint4 cell;
                cell.x = pack2h(v0.x, v0.y); cell.y = pack2h(v0.z, v0.w);
                cell.z = pack2h(v1.x, v1.y); cell.w = pack2h(v1.z, v1.w);
                ws2v[g][i][(pg + (i >> 2)) & 3] = cell;
            }
        }
        __syncthreads();
        #pragma unroll
        for (int pg = 0; pg < 4; ++pg) {
            uint4 wc[3][2];
            #pragma unroll
            for (int g = 0; g < 3; ++g)
                #pragma unroll
                for (int db = 0; db < 2; ++db) {
                    const int d = d_l + 64 * db;
                    wc[g][db] = ws2v[g][d][(pg + (d >> 2)) & 3];
                }
            #pragma unroll
            for (int p = 0; p < 4; ++p) {
                const int pair = 4 * pg + p;
                u32 x2[2][8];
                #pragma unroll
                for (int tt = 0; tt < 2; ++tt) {
                    const uint4* xr = (const uint4*)&xs2[tt][pair][bq * 8];
                    uint4 xa = xr[0], xb = xr[1];
                    x2[tt][0] = xa.x; x2[tt][1] = xa.y; x2[tt][2] = xa.z; x2[tt][3] = xa.w;
                    x2[tt][4] = xb.x; x2[tt][5] = xb.y; x2[tt][6] = xb.z; x2[tt][7] = xb.w;
                }
                u32 w[3][2];
                #pragma unroll
                for (int g = 0; g < 3; ++g)
                    #pragma unroll
                    for (int db = 0; db < 2; ++db) {
                        const uint4 v = wc[g][db];
                        w[g][db] = (p == 0) ? v.x : (p == 1) ? v.y : (p == 2) ? v.z : v.w;
                    }
                #pragma unroll
                for (int tt = 0; tt < 2; ++tt)
                    #pragma unroll
                    for (int db = 0; db < 2; ++db)
                        #pragma unroll
                        for (int j = 0; j < 8; ++j)
                            #pragma unroll
                            for (int g = 0; g < 3; ++g)
                                acc[tt][db][j][g] = fdot2(x2[tt][j], w[g][db], acc[tt][db][j][g]);
            }
        }
        __syncthreads();
    }

    #pragma unroll
    for (int db = 0; db < 2; ++db) {
        const int d = d0 + 64 * db + d_l;
        const float b0 = 2.0f * bi[d];
        const float b1 = bz[d] + bi[d];
        const float b2 = bo[d] + bi[d];
        #pragma unroll
        for (int tt = 0; tt < 2; ++tt)
            #pragma unroll
            for (int j = 0; j < 8; ++j) {
                const size_t o = ((size_t)(t0 + tt) * 32 + (bq * 8 + j)) * 512 + d;
                Xi[o] = f2h(acc[tt][db][j][0] + b0);
                Xz[o] = f2h(acc[tt][db][j][1] + b1);
                Xo[o] = f2h(acc[tt][db][j][2] + b2);
            }
    }
}

// ---------------------------------------------------------------------------
// K2 v6: full-K single-WG recurrence. One 512-thread WG per batch element,
// thread tid = output dim d, FULL K (256 f16-pairs) per thread.
// Weights live in 16 NAMED u32x16 SSA values (no array, no runtime index,
// no asm pins) so the compiler keeps them in 256 VGPRs — v4/v5 used a u32[128]
// array + asm pins, which went to scratch (VGPR_Count=64/84) and re-streamed
// 512 KB/CU/step from L2 (~9000 cy/step, the measured bottleneck).
// __launch_bounds__(512, 2): 2 waves/EU min -> 1024-VGPR budget, pressure
// ~330 fits with no spill.
// Full-K also removes the partial-sum exchange: ONE barrier per step,
// no pbuf, gate math on all waves. Accumulation is bit-identical to v4/v5:
// p0 = (a0+a1)+(a2+a3) over pairs 0..127, p1 = same over pairs 128..255,
// v = p0 + p1 (old "own + partner" order).
// ---------------------------------------------------------------------------
#define DOTC(HB, wv) do {                                                     \
    const uint4 hA = hv[(HB)+0], hBv = hv[(HB)+1],                            \
                hC = hv[(HB)+2], hD = hv[(HB)+3];                             \
    a0 = fdot2(hA.x, (wv)[0],  a0); a1 = fdot2(hA.y, (wv)[1],  a1);           \
    a2 = fdot2(hA.z, (wv)[2],  a2); a3 = fdot2(hA.w, (wv)[3],  a3);           \
    a0 = fdot2(hBv.x,(wv)[4],  a0); a1 = fdot2(hBv.y,(wv)[5],  a1);           \
    a2 = fdot2(hBv.z,(wv)[6],  a2); a3 = fdot2(hBv.w,(wv)[7],  a3);           \
    a0 = fdot2(hC.x, (wv)[8],  a0); a1 = fdot2(hC.y, (wv)[9],  a1);           \
    a2 = fdot2(hC.z, (wv)[10], a2); a3 = fdot2(hC.w, (wv)[11], a3);           \
    a0 = fdot2(hD.x, (wv)[12], a0); a1 = fdot2(hD.y, (wv)[13], a1);           \
    a2 = fdot2(hD.z, (wv)[14], a2); a3 = fdot2(hD.w, (wv)[15], a3);           \
} while (0)

__global__ __launch_bounds__(512, 2) void k2_recur(
    const u16* __restrict__ Xi, const u16* __restrict__ Xz, const u16* __restrict__ Xo,
    const u32* __restrict__ WpkT, const u32* __restrict__ Wypk,
    const float* __restrict__ by, float* __restrict__ out)
{
    __shared__ alignas(16) u16 hb[2][512];   // full h, f16, ping-pong

    const int b   = blockIdx.x;              // 0..31
    const int tid = threadIdx.x;             // = output dim d

    // full weight row for output d: 256 pairs = 16 named u32x16 (256 VGPRs)
    const u32x16* Wv = (const u32x16*)(WpkT + (size_t)tid * 256);
    u32x16 w0 = Wv[0],  w1 = Wv[1],  w2 = Wv[2],  w3 = Wv[3],
           w4 = Wv[4],  w5 = Wv[5],  w6 = Wv[6],  w7 = Wv[7],
           w8 = Wv[8],  w9 = Wv[9],  wA = Wv[10], wB = Wv[11],
           wC = Wv[12], wD = Wv[13], wE = Wv[14], wF = Wv[15];

    hb[0][tid] = (u16)0;                     // h = 0 at t = 0
    __syncthreads();

    u16 xi_c = Xi[(size_t)b * 512 + tid];
    u16 xz_c = Xz[(size_t)b * 512 + tid];
    u16 xo_c = Xo[(size_t)b * 512 + tid];

    float hn = 0.0f;
    for (int t = 0; t < 2048; ++t) {
        const int par = t & 1;

        // prefetch next-step x (latency hides under the dot)
        const int tn = (t + 1) & 2047;
        const size_t xb = ((size_t)tn * 32 + b) * 512 + tid;
        const u16 xi_n = Xi[xb], xz_n = Xz[xb], xo_n = Xo[xb];

        // full dot: h broadcast from LDS (wave-uniform addr), weights in regs
        const uint4* hv = (const uint4*)&hb[par][0];
        float a0, a1, a2, a3;

        a0 = a1 = a2 = a3 = 0.0f;            // pairs 0..127 (old "half 0")
        DOTC(0,  w0); DOTC(4,  w1); DOTC(8,  w2); DOTC(12, w3);
        DOTC(16, w4); DOTC(20, w5); DOTC(24, w6); DOTC(28, w7);
        const float p0 = (a0 + a1) + (a2 + a3);

        a0 = a1 = a2 = a3 = 0.0f;            // pairs 128..255 (old "half 1")
        DOTC(32, w8); DOTC(36, w9); DOTC(40, wA); DOTC(44, wB);
        DOTC(48, wC); DOTC(52, wD); DOTC(56, wE); DOTC(60, wF);
        const float p1 = (a0 + a1) + (a2 + a3);

        const float v = p0 + p1;             // same order as v4: own + partner

        const float zi = fsigmoid(h2f(xi_c) + v);
        const float z  = fsigmoid(h2f(xz_c) + v);
        const float zo = fsigmoid(h2f(xo_c) + v);
        hn = zo * ftanh_pos(zi * z);

        hb[par ^ 1][tid] = f2h(hn);          // publish h for step t+1
        __syncthreads();                     // single barrier per step

        xi_c = xi_n; xz_c = xz_n; xo_c = xo_n;
    }

    // epilogue: final h is in hb[0] (t=2047, par=1 wrote hb[0]).
    // Same arithmetic order as v4/v5's epilogue.
    {
        const uint4* hv = (const uint4*)&hb[0][0];
        float e0 = 0.f, e1 = 0.f, e2 = 0.f, e3 = 0.f;
        #pragma unroll 8
        for (int i = 0; i < 64; ++i) {
            const uint4 hc = hv[i];
            e0 = fdot2(hc.x, Wypk[(size_t)(4 * i + 0) * 512 + tid], e0);
            e1 = fdot2(hc.y, Wypk[(size_t)(4 * i + 1) * 512 + tid], e1);
            e2 = fdot2(hc.z, Wypk[(size_t)(4 * i + 2) * 512 + tid], e2);
            e3 = fdot2(hc.w, Wypk[(size_t)(4 * i + 3) * 512 + tid], e3);
        }
        out[(size_t)b * 512 + tid] = (e0 + e1) + (e2 + e3) + by[tid];
    }
}

// ---------------------------------------------------------------------------
extern "C" void kernel_launch(void* const* d_in, const int* in_sizes, int n_in,
                              void* d_out, int out_size, void* d_ws, size_t ws_size,
                              hipStream_t stream) {
    const float* word = (const float*)d_in[0];
    // d_in[1]=Wf, d_in[2]=bf : dead in the reference (c==0 path), unused.
    const float* Wi = (const float*)d_in[3];
    const float* bi = (const float*)d_in[4];
    const float* Wz = (const float*)d_in[5];
    const float* bz = (const float*)d_in[6];
    const float* Wo = (const float*)d_in[7];
    const float* bo = (const float*)d_in[8];
    const float* Wy = (const float*)d_in[9];
    const float* by = (const float*)d_in[10];
    float* out = (float*)d_out;

    char* ws = (char*)d_ws;
    const size_t XN = (size_t)2048 * 32 * 512 * sizeof(u16);  // 64 MB per gate array
    u16* Xi = (u16*)(ws);
    u16* Xz = (u16*)(ws + XN);
    u16* Xo = (u16*)(ws + 2 * XN);
    u32* WpkT = (u32*)(ws + 3 * XN);                          // 512 KB
    u32* Wypk = (u32*)(ws + 3 * XN + (size_t)524288);         // 512 KB

    k0_pack<<<768, 256, 0, stream>>>(Wi, Wy, WpkT, Wypk);

    dim3 g1(1024, 4);
    k1_gates<<<g1, 256, 0, stream>>>(word, Wi, Wz, Wo, bi, bz, bo, Xi, Xz, Xo);

    k2_recur<<<32, 512, 0, stream>>>(Xi, Xz, Xo, WpkT, Wypk, by, out);
}

// Round 3
// 8245.906 us; speedup vs baseline: 1.1839x; 1.0563x over previous
//
#include <hip/hip_runtime.h>

typedef unsigned int u32;
typedef unsigned short u16;
typedef unsigned long long u64;
typedef _Float16 f16;
typedef f16 f16x2 __attribute__((ext_vector_type(2)));
typedef u32 u32x16 __attribute__((ext_vector_type(16)));

__device__ __forceinline__ float fdot2(u32 a, u32 b, float c) {
#if __has_builtin(__builtin_amdgcn_fdot2)
    return __builtin_amdgcn_fdot2(__builtin_bit_cast(f16x2, a),
                                  __builtin_bit_cast(f16x2, b), c, false);
#else
    f16x2 av = __builtin_bit_cast(f16x2, a), bv = __builtin_bit_cast(f16x2, b);
    c += (float)av[0] * (float)bv[0];
    c += (float)av[1] * (float)bv[1];
    return c;
#endif
}

__device__ __forceinline__ u32 pack2h(float a, float b) {
    f16x2 h; h[0] = (f16)a; h[1] = (f16)b;
    return __builtin_bit_cast(u32, h);
}
__device__ __forceinline__ float h2f(u16 x) { return (float)__builtin_bit_cast(f16, x); }
__device__ __forceinline__ u16 f2h(float x) { f16 h = (f16)x; return __builtin_bit_cast(u16, h); }

__device__ __forceinline__ float fexp(float x) {
#if __has_builtin(__builtin_amdgcn_exp2f)
    return __builtin_amdgcn_exp2f(x * 1.44269504088896f);
#else
    return __expf(x);
#endif
}
__device__ __forceinline__ float frcp(float x) {
#if __has_builtin(__builtin_amdgcn_rcpf)
    return __builtin_amdgcn_rcpf(x);
#else
    return 1.0f / x;
#endif
}
__device__ __forceinline__ float fsigmoid(float x) { return frcp(1.0f + fexp(-x)); }
__device__ __forceinline__ float ftanh_pos(float x) { return 1.0f - 2.0f * frcp(fexp(2.0f * x) + 1.0f); }

// ---------------------------------------------------------------------------
// K0: pack weights to f16 pairs. (unchanged)
//   WpkT[d][p] = (Wi[d][2p], Wi[d][2p+1])   d<512, p<256   (row-major rows)
//   Wypk[p][d] = (Wy[d][2p], Wy[d][2p+1])   (K2 epilogue layout)
// ---------------------------------------------------------------------------
__global__ __launch_bounds__(256) void k0_pack(const float* __restrict__ Wi,
                                               const float* __restrict__ Wy,
                                               u32* __restrict__ WpkT,
                                               u32* __restrict__ Wypk) {
    const int bx = blockIdx.x, tid = threadIdx.x;
    if (bx < 512) {
        const float2 v = *(const float2*)(Wi + (size_t)bx * 512 + 2 * tid);
        WpkT[(size_t)bx * 256 + tid] = pack2h(v.x, v.y);
    } else {
        const int p = bx - 512;
        #pragma unroll
        for (int r = 0; r < 2; ++r) {
            const int d = tid + 256 * r;
            Wypk[(size_t)p * 512 + d] =
                pack2h(Wy[(size_t)d * 512 + 2 * p], Wy[(size_t)d * 512 + 2 * p + 1]);
        }
    }
}

// ---------------------------------------------------------------------------
// K1: gate pre-activations (parallel over all t). Unchanged.
// ---------------------------------------------------------------------------
__global__ __launch_bounds__(256) void k1_gates(
    const float* __restrict__ word,
    const float* __restrict__ Wi, const float* __restrict__ Wz, const float* __restrict__ Wo,
    const float* __restrict__ bi, const float* __restrict__ bz, const float* __restrict__ bo,
    u16* __restrict__ Xi, u16* __restrict__ Xz, u16* __restrict__ Xo)
{
    __shared__ uint4 ws2v[3][128][4];
    __shared__ u32 xs2[2][16][36];

    const int tid = threadIdx.x;
    const int d_l = tid & 63;
    const int bq  = tid >> 6;
    const int t0  = blockIdx.x * 2;
    const int d0  = blockIdx.y * 128;

    const float* Wg[3] = {Wi, Wz, Wo};

    float acc[2][2][8][3];
    #pragma unroll
    for (int tt = 0; tt < 2; ++tt)
        #pragma unroll
        for (int db = 0; db < 2; ++db)
            #pragma unroll
            for (int j = 0; j < 8; ++j)
                #pragma unroll
                for (int g = 0; g < 3; ++g) acc[tt][db][j][g] = 0.0f;

    for (int k0c = 0; k0c < 512; k0c += 32) {
        {
            const int p = tid & 15, bg = tid >> 4;
            #pragma unroll
            for (int tt = 0; tt < 2; ++tt)
                #pragma unroll
                for (int j = 0; j < 2; ++j) {
                    const int bb = bg * 2 + j;
                    const float2 v = *(const float2*)(word + (((size_t)(t0 + tt) * 32 + bb) * 512 + k0c + 2 * p));
                    xs2[tt][p][bb] = pack2h(v.x, v.y);
                }
        }
        {
            #pragma unroll
            for (int cc = 0; cc < 6; ++cc) {
                const int c = tid + 256 * cc;
                const int g = c >> 9, r = c & 511, pg = r >> 7, i = r & 127;
                const float* src = Wg[g] + (size_t)(d0 + i) * 512 + k0c + 8 * pg;
                const float4 v0 = ((const float4*)src)[0];
                const float4 v1 = ((const float4*)src)[1];
                uint4 cell;
                cell.x = pack2h(v0.x, v0.y); cell.y = pack2h(v0.z, v0.w);
                cell.z = pack2h(v1.x, v1.y); cell.w = pack2h(v1.z, v1.w);
                ws2v[g][i][(pg + (i >> 2)) & 3] = cell;
            }
        }
        __syncthreads();
        #pragma unroll
        for (int pg = 0; pg < 4; ++pg) {
            uint4 wc[3][2];
            #pragma unroll
            for (int g = 0; g < 3; ++g)
                #pragma unroll
                for (int db = 0; db < 2; ++db) {
                    const int d = d_l + 64 * db;
                    wc[g][db] = ws2v[g][d][(pg + (d >> 2)) & 3];
                }
            #pragma unroll
            for (int p = 0; p < 4; ++p) {
                const int pair = 4 * pg + p;
                u32 x2[2][8];
                #pragma unroll
                for (int tt = 0; tt < 2; ++tt) {
                    const uint4* xr = (const uint4*)&xs2[tt][pair][bq * 8];
                    uint4 xa = xr[0], xb = xr[1];
                    x2[tt][0] = xa.x; x2[tt][1] = xa.y; x2[tt][2] = xa.z; x2[tt][3] = xa.w;
                    x2[tt][4] = xb.x; x2[tt][5] = xb.y; x2[tt][6] = xb.z; x2[tt][7] = xb.w;
                }
                u32 w[3][2];
                #pragma unroll
                for (int g = 0; g < 3; ++g)
                    #pragma unroll
                    for (int db = 0; db < 2; ++db) {
                        const uint4 v = wc[g][db];
                        w[g][db] = (p == 0) ? v.x : (p == 1) ? v.y : (p == 2) ? v.z : v.w;
                    }
                #pragma unroll
                for (int tt = 0; tt < 2; ++tt)
                    #pragma unroll
                    for (int db = 0; db < 2; ++db)
                        #pragma unroll
                        for (int j = 0; j < 8; ++j)
                            #pragma unroll
                            for (int g = 0; g < 3; ++g)
                                acc[tt][db][j][g] = fdot2(x2[tt][j], w[g][db], acc[tt][db][j][g]);
            }
        }
        __syncthreads();
    }

    #pragma unroll
    for (int db = 0; db < 2; ++db) {
        const int d = d0 + 64 * db + d_l;
        const float b0 = 2.0f * bi[d];
        const float b1 = bz[d] + bi[d];
        const float b2 = bo[d] + bi[d];
        #pragma unroll
        for (int tt = 0; tt < 2; ++tt)
            #pragma unroll
            for (int j = 0; j < 8; ++j) {
                const size_t o = ((size_t)(t0 + tt) * 32 + (bq * 8 + j)) * 512 + d;
                Xi[o] = f2h(acc[tt][db][j][0] + b0);
                Xz[o] = f2h(acc[tt][db][j][1] + b1);
                Xo[o] = f2h(acc[tt][db][j][2] + b2);
            }
    }
}

// ---------------------------------------------------------------------------
// K2 v7: K-split × output-block recurrence. One 512-thread WG per batch.
// Thread (dg = tid>>3, ks = tid&7): partial dots for 8 outputs {8dg..8dg+7}
// over K-slice ks (pairs [32ks,32ks+32)). Fixes two measured bottlenecks:
//  (a) weight residency: 16 named u32x16 loaded ONCE then made opaque via
//      asm "+v" pins -> compiler cannot re-materialize the loads in the loop
//      (v6: VGPR_Count=128, 1KB/thread/step re-streamed from L2).
//      __launch_bounds__(512,1) caps allocator at 512 VGPR; pressure ~320.
//  (b) LDS broadcast pressure: h-reads drop 512 -> 64 ds_read_b128/CU/step
//      (each read feeds 8 outputs). Slice stride 72 u16 (144B) de-conflicts
//      the 8 broadcast groups per instruction across bank quads.
// Per-output partials reduced IN-WAVE by a 3-stage shfl_xor butterfly over
// the 8-lane group; lane tid ends holding output d == tid. One barrier/step.
// ---------------------------------------------------------------------------
#define HSTR 72   // u16 stride per 64-element h slice (144 B, bank-deconflict)

#define DOTR(hc, c, A, WA) \
    A = fdot2(hc.x, WA[4*((c)&3)+0], A); A = fdot2(hc.y, WA[4*((c)&3)+1], A); \
    A = fdot2(hc.z, WA[4*((c)&3)+2], A); A = fdot2(hc.w, WA[4*((c)&3)+3], A);

#define DOTC(c, V) do { const uint4 hc = hv[c];                                \
    DOTR(hc, c, a0, wr0##V) DOTR(hc, c, a1, wr1##V)                            \
    DOTR(hc, c, a2, wr2##V) DOTR(hc, c, a3, wr3##V)                            \
    DOTR(hc, c, a4, wr4##V) DOTR(hc, c, a5, wr5##V)                            \
    DOTR(hc, c, a6, wr6##V) DOTR(hc, c, a7, wr7##V) } while (0)

__global__ __launch_bounds__(512, 1) void k2_recur(
    const u16* __restrict__ Xi, const u16* __restrict__ Xz, const u16* __restrict__ Xo,
    const u32* __restrict__ WpkT, const u32* __restrict__ Wypk,
    const float* __restrict__ by, float* __restrict__ out)
{
    __shared__ alignas(16) u16 hb[2][8 * HSTR];   // strided h, f16, ping-pong

    const int b   = blockIdx.x;                   // 0..31
    const int tid = threadIdx.x;
    const int dg  = tid >> 3;                     // output group (8 outputs)
    const int ks  = tid & 7;                      // K-slice

    // weights: rows 8dg..8dg+7, pairs [32ks, 32ks+32) -> 16 named u32x16
    const u32* Wb = WpkT + (size_t)(8 * dg) * 256 + 32 * ks;
    u32x16 wr0a = *(const u32x16*)(Wb + 0 * 256),      wr0b = *(const u32x16*)(Wb + 0 * 256 + 16);
    u32x16 wr1a = *(const u32x16*)(Wb + 1 * 256),      wr1b = *(const u32x16*)(Wb + 1 * 256 + 16);
    u32x16 wr2a = *(const u32x16*)(Wb + 2 * 256),      wr2b = *(const u32x16*)(Wb + 2 * 256 + 16);
    u32x16 wr3a = *(const u32x16*)(Wb + 3 * 256),      wr3b = *(const u32x16*)(Wb + 3 * 256 + 16);
    u32x16 wr4a = *(const u32x16*)(Wb + 4 * 256),      wr4b = *(const u32x16*)(Wb + 4 * 256 + 16);
    u32x16 wr5a = *(const u32x16*)(Wb + 5 * 256),      wr5b = *(const u32x16*)(Wb + 5 * 256 + 16);
    u32x16 wr6a = *(const u32x16*)(Wb + 6 * 256),      wr6b = *(const u32x16*)(Wb + 6 * 256 + 16);
    u32x16 wr7a = *(const u32x16*)(Wb + 7 * 256),      wr7b = *(const u32x16*)(Wb + 7 * 256 + 16);
    // opaque pins: values can no longer be re-materialized from memory
    asm volatile("" : "+v"(wr0a)); asm volatile("" : "+v"(wr0b));
    asm volatile("" : "+v"(wr1a)); asm volatile("" : "+v"(wr1b));
    asm volatile("" : "+v"(wr2a)); asm volatile("" : "+v"(wr2b));
    asm volatile("" : "+v"(wr3a)); asm volatile("" : "+v"(wr3b));
    asm volatile("" : "+v"(wr4a)); asm volatile("" : "+v"(wr4b));
    asm volatile("" : "+v"(wr5a)); asm volatile("" : "+v"(wr5b));
    asm volatile("" : "+v"(wr6a)); asm volatile("" : "+v"(wr6b));
    asm volatile("" : "+v"(wr7a)); asm volatile("" : "+v"(wr7b));

    // h = 0 at t = 0 (zero the full strided buffer incl. pads)
    hb[0][tid] = (u16)0;
    if (tid < 8 * HSTR - 512) hb[0][512 + tid] = (u16)0;
    __syncthreads();

    u16 xi_c = Xi[(size_t)b * 512 + tid];
    u16 xz_c = Xz[(size_t)b * 512 + tid];
    u16 xo_c = Xo[(size_t)b * 512 + tid];

    const int hwr = (tid >> 6) * HSTR + (tid & 63);   // strided publish slot
    const int sb0 = tid & 1, sb1 = tid & 2, sb2 = tid & 4;

    float hn = 0.0f;
    for (int t = 0; t < 2048; ++t) {
        const int par = t & 1;

        // prefetch next-step x (latency hides under the dot)
        const int tn = (t + 1) & 2047;
        const size_t xb = ((size_t)tn * 32 + b) * 512 + tid;
        const u16 xi_n = Xi[xb], xz_n = Xz[xb], xo_n = Xo[xb];

        // partial dots: 8 outputs over this thread's 32-pair K-slice
        const uint4* hv = (const uint4*)(&hb[par][0] + ks * HSTR);
        float a0 = 0.f, a1 = 0.f, a2 = 0.f, a3 = 0.f,
              a4 = 0.f, a5 = 0.f, a6 = 0.f, a7 = 0.f;
        DOTC(0, a); DOTC(1, a); DOTC(2, a); DOTC(3, a);
        DOTC(4, b); DOTC(5, b); DOTC(6, b); DOTC(7, b);

        // 3-stage in-wave butterfly over the 8-lane group: lane tid ends with
        // the full dot for output d == tid (slot l3 = 4*b2 + 2*b1 + b0).
        float q0, q1, q2, q3;
        {
            float s, k;
            s = sb0 ? a0 : a1; k = sb0 ? a1 : a0; q0 = k + __shfl_xor(s, 1);
            s = sb0 ? a2 : a3; k = sb0 ? a3 : a2; q1 = k + __shfl_xor(s, 1);
            s = sb0 ? a4 : a5; k = sb0 ? a5 : a4; q2 = k + __shfl_xor(s, 1);
            s = sb0 ? a6 : a7; k = sb0 ? a7 : a6; q3 = k + __shfl_xor(s, 1);
        }
        float r0, r1;
        {
            float s, k;
            s = sb1 ? q0 : q1; k = sb1 ? q1 : q0; r0 = k + __shfl_xor(s, 2);
            s = sb1 ? q2 : q3; k = sb1 ? q3 : q2; r1 = k + __shfl_xor(s, 2);
        }
        float v;
        {
            float s = sb2 ? r0 : r1, k = sb2 ? r1 : r0;
            v = k + __shfl_xor(s, 4);
        }

        const float zi = fsigmoid(h2f(xi_c) + v);
        const float z  = fsigmoid(h2f(xz_c) + v);
        const float zo = fsigmoid(h2f(xo_c) + v);
        hn = zo * ftanh_pos(zi * z);

        hb[par ^ 1][hwr] = f2h(hn);          // publish h for step t+1
        __syncthreads();                     // single barrier per step

        xi_c = xi_n; xz_c = xz_n; xo_c = xo_n;
    }

    // epilogue: final h is in hb[0] (t=2047, par=1 wrote hb[0]).
    // Same accumulation order as v6 (global chunk i = 8s+c ascending).
    {
        float e0 = 0.f, e1 = 0.f, e2 = 0.f, e3 = 0.f;
        #pragma unroll
        for (int s = 0; s < 8; ++s) {
            const uint4* hv0 = (const uint4*)(&hb[0][0] + s * HSTR);
            #pragma unroll
            for (int c = 0; c < 8; ++c) {
                const uint4 hc = hv0[c];
                const int i = 8 * s + c;
                e0 = fdot2(hc.x, Wypk[(size_t)(4 * i + 0) * 512 + tid], e0);
                e1 = fdot2(hc.y, Wypk[(size_t)(4 * i + 1) * 512 + tid], e1);
                e2 = fdot2(hc.z, Wypk[(size_t)(4 * i + 2) * 512 + tid], e2);
                e3 = fdot2(hc.w, Wypk[(size_t)(4 * i + 3) * 512 + tid], e3);
            }
        }
        out[(size_t)b * 512 + tid] = (e0 + e1) + (e2 + e3) + by[tid];
    }
}

// ---------------------------------------------------------------------------
extern "C" void kernel_launch(void* const* d_in, const int* in_sizes, int n_in,
                              void* d_out, int out_size, void* d_ws, size_t ws_size,
                              hipStream_t stream) {
    const float* word = (const float*)d_in[0];
    // d_in[1]=Wf, d_in[2]=bf : dead in the reference (c==0 path), unused.
    const float* Wi = (const float*)d_in[3];
    const float* bi = (const float*)d_in[4];
    const float* Wz = (const float*)d_in[5];
    const float* bz = (const float*)d_in[6];
    const float* Wo = (const float*)d_in[7];
    const float* bo = (const float*)d_in[8];
    const float* Wy = (const float*)d_in[9];
    const float* by = (const float*)d_in[10];
    float* out = (float*)d_out;

    char* ws = (char*)d_ws;
    const size_t XN = (size_t)2048 * 32 * 512 * sizeof(u16);  // 64 MB per gate array
    u16* Xi = (u16*)(ws);
    u16* Xz = (u16*)(ws + XN);
    u16* Xo = (u16*)(ws + 2 * XN);
    u32* WpkT = (u32*)(ws + 3 * XN);                          // 512 KB
    u32* Wypk = (u32*)(ws + 3 * XN + (size_t)524288);         // 512 KB

    k0_pack<<<768, 256, 0, stream>>>(Wi, Wy, WpkT, Wypk);

    dim3 g1(1024, 4);
    k1_gates<<<g1, 256, 0, stream>>>(word, Wi, Wz, Wo, bi, bz, bo, Xi, Xz, Xo);

    k2_recur<<<32, 512, 0, stream>>>(Xi, Xz, Xo, WpkT, Wypk, by, out);
}

// Round 4
// 8231.438 us; speedup vs baseline: 1.1860x; 1.0018x over previous
//
#include <hip/hip_runtime.h>

typedef unsigned int u32;
typedef unsigned short u16;
typedef unsigned long long u64;
typedef _Float16 f16;
typedef f16 f16x2 __attribute__((ext_vector_type(2)));
typedef u32 u32x16 __attribute__((ext_vector_type(16)));

__device__ __forceinline__ float fdot2(u32 a, u32 b, float c) {
#if __has_builtin(__builtin_amdgcn_fdot2)
    return __builtin_amdgcn_fdot2(__builtin_bit_cast(f16x2, a),
                                  __builtin_bit_cast(f16x2, b), c, false);
#else
    f16x2 av = __builtin_bit_cast(f16x2, a), bv = __builtin_bit_cast(f16x2, b);
    c += (float)av[0] * (float)bv[0];
    c += (float)av[1] * (float)bv[1];
    return c;
#endif
}

__device__ __forceinline__ u32 pack2h(float a, float b) {
    f16x2 h; h[0] = (f16)a; h[1] = (f16)b;
    return __builtin_bit_cast(u32, h);
}
__device__ __forceinline__ float h2f(u16 x) { return (float)__builtin_bit_cast(f16, x); }
__device__ __forceinline__ u16 f2h(float x) { f16 h = (f16)x; return __builtin_bit_cast(u16, h); }

__device__ __forceinline__ float fexp(float x) {
#if __has_builtin(__builtin_amdgcn_exp2f)
    return __builtin_amdgcn_exp2f(x * 1.44269504088896f);
#else
    return __expf(x);
#endif
}
__device__ __forceinline__ float frcp(float x) {
#if __has_builtin(__builtin_amdgcn_rcpf)
    return __builtin_amdgcn_rcpf(x);
#else
    return 1.0f / x;
#endif
}
__device__ __forceinline__ float fsigmoid(float x) { return frcp(1.0f + fexp(-x)); }
__device__ __forceinline__ float ftanh_pos(float x) { return 1.0f - 2.0f * frcp(fexp(2.0f * x) + 1.0f); }

// ---------------------------------------------------------------------------
// K0: pack weights to f16 pairs. (unchanged)
//   WpkT[d][p] = (Wi[d][2p], Wi[d][2p+1])   d<512, p<256   (row-major rows)
//   Wypk[p][d] = (Wy[d][2p], Wy[d][2p+1])   (K2 epilogue layout)
// ---------------------------------------------------------------------------
__global__ __launch_bounds__(256) void k0_pack(const float* __restrict__ Wi,
                                               const float* __restrict__ Wy,
                                               u32* __restrict__ WpkT,
                                               u32* __restrict__ Wypk) {
    const int bx = blockIdx.x, tid = threadIdx.x;
    if (bx < 512) {
        const float2 v = *(const float2*)(Wi + (size_t)bx * 512 + 2 * tid);
        WpkT[(size_t)bx * 256 + tid] = pack2h(v.x, v.y);
    } else {
        const int p = bx - 512;
        #pragma unroll
        for (int r = 0; r < 2; ++r) {
            const int d = tid + 256 * r;
            Wypk[(size_t)p * 512 + d] =
                pack2h(Wy[(size_t)d * 512 + 2 * p], Wy[(size_t)d * 512 + 2 * p + 1]);
        }
    }
}

// ---------------------------------------------------------------------------
// K1: gate pre-activations (parallel over all t). Unchanged.
// ---------------------------------------------------------------------------
__global__ __launch_bounds__(256) void k1_gates(
    const float* __restrict__ word,
    const float* __restrict__ Wi, const float* __restrict__ Wz, const float* __restrict__ Wo,
    const float* __restrict__ bi, const float* __restrict__ bz, const float* __restrict__ bo,
    u16* __restrict__ Xi, u16* __restrict__ Xz, u16* __restrict__ Xo)
{
    __shared__ uint4 ws2v[3][128][4];
    __shared__ u32 xs2[2][16][36];

    const int tid = threadIdx.x;
    const int d_l = tid & 63;
    const int bq  = tid >> 6;
    const int t0  = blockIdx.x * 2;
    const int d0  = blockIdx.y * 128;

    const float* Wg[3] = {Wi, Wz, Wo};

    float acc[2][2][8][3];
    #pragma unroll
    for (int tt = 0; tt < 2; ++tt)
        #pragma unroll
        for (int db = 0; db < 2; ++db)
            #pragma unroll
            for (int j = 0; j < 8; ++j)
                #pragma unroll
                for (int g = 0; g < 3; ++g) acc[tt][db][j][g] = 0.0f;

    for (int k0c = 0; k0c < 512; k0c += 32) {
        {
            const int p = tid & 15, bg = tid >> 4;
            #pragma unroll
            for (int tt = 0; tt < 2; ++tt)
                #pragma unroll
                for (int j = 0; j < 2; ++j) {
                    const int bb = bg * 2 + j;
                    const float2 v = *(const float2*)(word + (((size_t)(t0 + tt) * 32 + bb) * 512 + k0c + 2 * p));
                    xs2[tt][p][bb] = pack2h(v.x, v.y);
                }
        }
        {
            #pragma unroll
            for (int cc = 0; cc < 6; ++cc) {
                const int c = tid + 256 * cc;
                const int g = c >> 9, r = c & 511, pg = r >> 7, i = r & 127;
                const float* src = Wg[g] + (size_t)(d0 + i) * 512 + k0c + 8 * pg;
                const float4 v0 = ((const float4*)src)[0];
                const float4 v1 = ((const float4*)src)[1];
                uint4 cell;
                cell.x = pack2h(v0.x, v0.y); cell.y = pack2h(v0.z, v0.w);
                cell.z = pack2h(v1.x, v1.y); cell.w = pack2h(v1.z, v1.w);
                ws2v[g][i][(pg + (i >> 2)) & 3] = cell;
            }
        }
        __syncthreads();
        #pragma unroll
        for (int pg = 0; pg < 4; ++pg) {
            uint4 wc[3][2];
            #pragma unroll
            for (int g = 0; g < 3; ++g)
                #pragma unroll
                for (int db = 0; db < 2; ++db) {
                    const int d = d_l + 64 * db;
                    wc[g][db] = ws2v[g][d][(pg + (d >> 2)) & 3];
                }
            #pragma unroll
            for (int p = 0; p < 4; ++p) {
                const int pair = 4 * pg + p;
                u32 x2[2][8];
                #pragma unroll
                for (int tt = 0; tt < 2; ++tt) {
                    const uint4* xr = (const uint4*)&xs2[tt][pair][bq * 8];
                    uint4 xa = xr[0], xb = xr[1];
                    x2[tt][0] = xa.x; x2[tt][1] = xa.y; x2[tt][2] = xa.z; x2[tt][3] = xa.w;
                    x2[tt][4] = xb.x; x2[tt][5] = xb.y; x2[tt][6] = xb.z; x2[tt][7] = xb.w;
                }
                u32 w[3][2];
                #pragma unroll
                for (int g = 0; g < 3; ++g)
                    #pragma unroll
                    for (int db = 0; db < 2; ++db) {
                        const uint4 v = wc[g][db];
                        w[g][db] = (p == 0) ? v.x : (p == 1) ? v.y : (p == 2) ? v.z : v.w;
                    }
                #pragma unroll
                for (int tt = 0; tt < 2; ++tt)
                    #pragma unroll
                    for (int db = 0; db < 2; ++db)
                        #pragma unroll
                        for (int j = 0; j < 8; ++j)
                            #pragma unroll
                            for (int g = 0; g < 3; ++g)
                                acc[tt][db][j][g] = fdot2(x2[tt][j], w[g][db], acc[tt][db][j][g]);
            }
        }
        __syncthreads();
    }

    #pragma unroll
    for (int db = 0; db < 2; ++db) {
        const int d = d0 + 64 * db + d_l;
        const float b0 = 2.0f * bi[d];
        const float b1 = bz[d] + bi[d];
        const float b2 = bo[d] + bi[d];
        #pragma unroll
        for (int tt = 0; tt < 2; ++tt)
            #pragma unroll
            for (int j = 0; j < 8; ++j) {
                const size_t o = ((size_t)(t0 + tt) * 32 + (bq * 8 + j)) * 512 + d;
                Xi[o] = f2h(acc[tt][db][j][0] + b0);
                Xz[o] = f2h(acc[tt][db][j][1] + b1);
                Xo[o] = f2h(acc[tt][db][j][2] + b2);
            }
    }
}

// ---------------------------------------------------------------------------
// K2 v8: identical structure to v7 (K-split x output-block, in-wave butterfly,
// one barrier/step) with ONE change: amdgpu_waves_per_eu(2,2).
// Post-mortem of v5-v7: all three compiled to VGPR_Count in {64,84,128} --
// the RA targets HIGH occupancy (8 waves/SIMD -> <=256 VGPR budget) and
// spills the 256 weight u32 to scratch, re-streaming 1KB/thread/step from L2
// (~8200 cy/step, the measured bottleneck). asm pins block rematerialization
// but NOT spilling. waves_per_eu(2,2) clamps the occupancy target to our
// actual occupancy (one 512-thread WG per CU = 2 waves/EU), raising the
// allocator budget to the HW max 512 VGPR/wave; in-loop pressure ~310 fits.
// ---------------------------------------------------------------------------
#define HSTR 72   // u16 stride per 64-element h slice (144 B, bank-deconflict)

#define DOTR(hc, c, A, WA) \
    A = fdot2(hc.x, WA[4*((c)&3)+0], A); A = fdot2(hc.y, WA[4*((c)&3)+1], A); \
    A = fdot2(hc.z, WA[4*((c)&3)+2], A); A = fdot2(hc.w, WA[4*((c)&3)+3], A);

#define DOTC(c, V) do { const uint4 hc = hv[c];                                \
    DOTR(hc, c, a0, wr0##V) DOTR(hc, c, a1, wr1##V)                            \
    DOTR(hc, c, a2, wr2##V) DOTR(hc, c, a3, wr3##V)                            \
    DOTR(hc, c, a4, wr4##V) DOTR(hc, c, a5, wr5##V)                            \
    DOTR(hc, c, a6, wr6##V) DOTR(hc, c, a7, wr7##V) } while (0)

__global__ __launch_bounds__(512)
__attribute__((amdgpu_waves_per_eu(2, 2)))
void k2_recur(
    const u16* __restrict__ Xi, const u16* __restrict__ Xz, const u16* __restrict__ Xo,
    const u32* __restrict__ WpkT, const u32* __restrict__ Wypk,
    const float* __restrict__ by, float* __restrict__ out)
{
    __shared__ alignas(16) u16 hb[2][8 * HSTR];   // strided h, f16, ping-pong

    const int b   = blockIdx.x;                   // 0..31
    const int tid = threadIdx.x;
    const int dg  = tid >> 3;                     // output group (8 outputs)
    const int ks  = tid & 7;                      // K-slice

    // weights: rows 8dg..8dg+7, pairs [32ks, 32ks+32) -> 16 named u32x16
    const u32* Wb = WpkT + (size_t)(8 * dg) * 256 + 32 * ks;
    u32x16 wr0a = *(const u32x16*)(Wb + 0 * 256),      wr0b = *(const u32x16*)(Wb + 0 * 256 + 16);
    u32x16 wr1a = *(const u32x16*)(Wb + 1 * 256),      wr1b = *(const u32x16*)(Wb + 1 * 256 + 16);
    u32x16 wr2a = *(const u32x16*)(Wb + 2 * 256),      wr2b = *(const u32x16*)(Wb + 2 * 256 + 16);
    u32x16 wr3a = *(const u32x16*)(Wb + 3 * 256),      wr3b = *(const u32x16*)(Wb + 3 * 256 + 16);
    u32x16 wr4a = *(const u32x16*)(Wb + 4 * 256),      wr4b = *(const u32x16*)(Wb + 4 * 256 + 16);
    u32x16 wr5a = *(const u32x16*)(Wb + 5 * 256),      wr5b = *(const u32x16*)(Wb + 5 * 256 + 16);
    u32x16 wr6a = *(const u32x16*)(Wb + 6 * 256),      wr6b = *(const u32x16*)(Wb + 6 * 256 + 16);
    u32x16 wr7a = *(const u32x16*)(Wb + 7 * 256),      wr7b = *(const u32x16*)(Wb + 7 * 256 + 16);
    // opaque pins: values can no longer be re-materialized from memory
    asm volatile("" : "+v"(wr0a)); asm volatile("" : "+v"(wr0b));
    asm volatile("" : "+v"(wr1a)); asm volatile("" : "+v"(wr1b));
    asm volatile("" : "+v"(wr2a)); asm volatile("" : "+v"(wr2b));
    asm volatile("" : "+v"(wr3a)); asm volatile("" : "+v"(wr3b));
    asm volatile("" : "+v"(wr4a)); asm volatile("" : "+v"(wr4b));
    asm volatile("" : "+v"(wr5a)); asm volatile("" : "+v"(wr5b));
    asm volatile("" : "+v"(wr6a)); asm volatile("" : "+v"(wr6b));
    asm volatile("" : "+v"(wr7a)); asm volatile("" : "+v"(wr7b));

    // h = 0 at t = 0 (zero the full strided buffer incl. pads)
    hb[0][tid] = (u16)0;
    if (tid < 8 * HSTR - 512) hb[0][512 + tid] = (u16)0;
    __syncthreads();

    u16 xi_c = Xi[(size_t)b * 512 + tid];
    u16 xz_c = Xz[(size_t)b * 512 + tid];
    u16 xo_c = Xo[(size_t)b * 512 + tid];

    const int hwr = (tid >> 6) * HSTR + (tid & 63);   // strided publish slot
    const int sb0 = tid & 1, sb1 = tid & 2, sb2 = tid & 4;

    float hn = 0.0f;
    for (int t = 0; t < 2048; ++t) {
        const int par = t & 1;

        // prefetch next-step x (latency hides under the dot)
        const int tn = (t + 1) & 2047;
        const size_t xb = ((size_t)tn * 32 + b) * 512 + tid;
        const u16 xi_n = Xi[xb], xz_n = Xz[xb], xo_n = Xo[xb];

        // partial dots: 8 outputs over this thread's 32-pair K-slice
        const uint4* hv = (const uint4*)(&hb[par][0] + ks * HSTR);
        float a0 = 0.f, a1 = 0.f, a2 = 0.f, a3 = 0.f,
              a4 = 0.f, a5 = 0.f, a6 = 0.f, a7 = 0.f;
        DOTC(0, a); DOTC(1, a); DOTC(2, a); DOTC(3, a);
        DOTC(4, b); DOTC(5, b); DOTC(6, b); DOTC(7, b);

        // 3-stage in-wave butterfly over the 8-lane group: lane tid ends with
        // the full dot for output d == tid (slot l3 = 4*b2 + 2*b1 + b0).
        float q0, q1, q2, q3;
        {
            float s, k;
            s = sb0 ? a0 : a1; k = sb0 ? a1 : a0; q0 = k + __shfl_xor(s, 1);
            s = sb0 ? a2 : a3; k = sb0 ? a3 : a2; q1 = k + __shfl_xor(s, 1);
            s = sb0 ? a4 : a5; k = sb0 ? a5 : a4; q2 = k + __shfl_xor(s, 1);
            s = sb0 ? a6 : a7; k = sb0 ? a7 : a6; q3 = k + __shfl_xor(s, 1);
        }
        float r0, r1;
        {
            float s, k;
            s = sb1 ? q0 : q1; k = sb1 ? q1 : q0; r0 = k + __shfl_xor(s, 2);
            s = sb1 ? q2 : q3; k = sb1 ? q3 : q2; r1 = k + __shfl_xor(s, 2);
        }
        float v;
        {
            float s = sb2 ? r0 : r1, k = sb2 ? r1 : r0;
            v = k + __shfl_xor(s, 4);
        }

        const float zi = fsigmoid(h2f(xi_c) + v);
        const float z  = fsigmoid(h2f(xz_c) + v);
        const float zo = fsigmoid(h2f(xo_c) + v);
        hn = zo * ftanh_pos(zi * z);

        hb[par ^ 1][hwr] = f2h(hn);          // publish h for step t+1
        __syncthreads();                     // single barrier per step

        xi_c = xi_n; xz_c = xz_n; xo_c = xo_n;
    }

    // epilogue: final h is in hb[0] (t=2047, par=1 wrote hb[0]).
    // Same accumulation order as v6 (global chunk i = 8s+c ascending).
    {
        float e0 = 0.f, e1 = 0.f, e2 = 0.f, e3 = 0.f;
        #pragma unroll
        for (int s = 0; s < 8; ++s) {
            const uint4* hv0 = (const uint4*)(&hb[0][0] + s * HSTR);
            #pragma unroll
            for (int c = 0; c < 8; ++c) {
                const uint4 hc = hv0[c];
                const int i = 8 * s + c;
                e0 = fdot2(hc.x, Wypk[(size_t)(4 * i + 0) * 512 + tid], e0);
                e1 = fdot2(hc.y, Wypk[(size_t)(4 * i + 1) * 512 + tid], e1);
                e2 = fdot2(hc.z, Wypk[(size_t)(4 * i + 2) * 512 + tid], e2);
                e3 = fdot2(hc.w, Wypk[(size_t)(4 * i + 3) * 512 + tid], e3);
            }
        }
        out[(size_t)b * 512 + tid] = (e0 + e1) + (e2 + e3) + by[tid];
    }
}

// ---------------------------------------------------------------------------
extern "C" void kernel_launch(void* const* d_in, const int* in_sizes, int n_in,
                              void* d_out, int out_size, void* d_ws, size_t ws_size,
                              hipStream_t stream) {
    const float* word = (const float*)d_in[0];
    // d_in[1]=Wf, d_in[2]=bf : dead in the reference (c==0 path), unused.
    const float* Wi = (const float*)d_in[3];
    const float* bi = (const float*)d_in[4];
    const float* Wz = (const float*)d_in[5];
    const float* bz = (const float*)d_in[6];
    const float* Wo = (const float*)d_in[7];
    const float* bo = (const float*)d_in[8];
    const float* Wy = (const float*)d_in[9];
    const float* by = (const float*)d_in[10];
    float* out = (float*)d_out;

    char* ws = (char*)d_ws;
    const size_t XN = (size_t)2048 * 32 * 512 * sizeof(u16);  // 64 MB per gate array
    u16* Xi = (u16*)(ws);
    u16* Xz = (u16*)(ws + XN);
    u16* Xo = (u16*)(ws + 2 * XN);
    u32* WpkT = (u32*)(ws + 3 * XN);                          // 512 KB
    u32* Wypk = (u32*)(ws + 3 * XN + (size_t)524288);         // 512 KB

    k0_pack<<<768, 256, 0, stream>>>(Wi, Wy, WpkT, Wypk);

    dim3 g1(1024, 4);
    k1_gates<<<g1, 256, 0, stream>>>(word, Wi, Wz, Wo, bi, bz, bo, Xi, Xz, Xo);

    k2_recur<<<32, 512, 0, stream>>>(Xi, Xz, Xo, WpkT, Wypk, by, out);
}

// Round 6
// 6162.581 us; speedup vs baseline: 1.5842x; 1.3357x over previous
//
#include <hip/hip_runtime.h>

typedef unsigned int u32;
typedef unsigned short u16;
typedef unsigned long long u64;
typedef _Float16 f16;
typedef f16 f16x2 __attribute__((ext_vector_type(2)));
typedef u32 u32x4 __attribute__((ext_vector_type(4)));   // asm-pinnable quad

__device__ __forceinline__ float fdot2(u32 a, u32 b, float c) {
#if __has_builtin(__builtin_amdgcn_fdot2)
    return __builtin_amdgcn_fdot2(__builtin_bit_cast(f16x2, a),
                                  __builtin_bit_cast(f16x2, b), c, false);
#else
    f16x2 av = __builtin_bit_cast(f16x2, a), bv = __builtin_bit_cast(f16x2, b);
    c += (float)av[0] * (float)bv[0];
    c += (float)av[1] * (float)bv[1];
    return c;
#endif
}

__device__ __forceinline__ u32 pack2h(float a, float b) {
    f16x2 h; h[0] = (f16)a; h[1] = (f16)b;
    return __builtin_bit_cast(u32, h);
}
__device__ __forceinline__ float h2f(u16 x) { return (float)__builtin_bit_cast(f16, x); }
__device__ __forceinline__ u16 f2h(float x) { f16 h = (f16)x; return __builtin_bit_cast(u16, h); }

__device__ __forceinline__ float fexp(float x) {
#if __has_builtin(__builtin_amdgcn_exp2f)
    return __builtin_amdgcn_exp2f(x * 1.44269504088896f);
#else
    return __expf(x);
#endif
}
__device__ __forceinline__ float frcp(float x) {
#if __has_builtin(__builtin_amdgcn_rcpf)
    return __builtin_amdgcn_rcpf(x);
#else
    return 1.0f / x;
#endif
}
__device__ __forceinline__ float fsigmoid(float x) { return frcp(1.0f + fexp(-x)); }
__device__ __forceinline__ float ftanh_pos(float x) { return 1.0f - 2.0f * frcp(fexp(2.0f * x) + 1.0f); }

// ---------------------------------------------------------------------------
// K0: pack weights to f16 pairs. (unchanged)
//   WpkT[d][p] = (Wi[d][2p], Wi[d][2p+1])   d<512, p<256   (row-major rows)
//   Wypk[p][d] = (Wy[d][2p], Wy[d][2p+1])   (K2 epilogue layout)
// ---------------------------------------------------------------------------
__global__ __launch_bounds__(256) void k0_pack(const float* __restrict__ Wi,
                                               const float* __restrict__ Wy,
                                               u32* __restrict__ WpkT,
                                               u32* __restrict__ Wypk) {
    const int bx = blockIdx.x, tid = threadIdx.x;
    if (bx < 512) {
        const float2 v = *(const float2*)(Wi + (size_t)bx * 512 + 2 * tid);
        WpkT[(size_t)bx * 256 + tid] = pack2h(v.x, v.y);
    } else {
        const int p = bx - 512;
        #pragma unroll
        for (int r = 0; r < 2; ++r) {
            const int d = tid + 256 * r;
            Wypk[(size_t)p * 512 + d] =
                pack2h(Wy[(size_t)d * 512 + 2 * p], Wy[(size_t)d * 512 + 2 * p + 1]);
        }
    }
}

// ---------------------------------------------------------------------------
// K1: gate pre-activations (parallel over all t). Unchanged.
// ---------------------------------------------------------------------------
__global__ __launch_bounds__(256) void k1_gates(
    const float* __restrict__ word,
    const float* __restrict__ Wi, const float* __restrict__ Wz, const float* __restrict__ Wo,
    const float* __restrict__ bi, const float* __restrict__ bz, const float* __restrict__ bo,
    u16* __restrict__ Xi, u16* __restrict__ Xz, u16* __restrict__ Xo)
{
    __shared__ uint4 ws2v[3][128][4];
    __shared__ u32 xs2[2][16][36];

    const int tid = threadIdx.x;
    const int d_l = tid & 63;
    const int bq  = tid >> 6;
    const int t0  = blockIdx.x * 2;
    const int d0  = blockIdx.y * 128;

    const float* Wg[3] = {Wi, Wz, Wo};

    float acc[2][2][8][3];
    #pragma unroll
    for (int tt = 0; tt < 2; ++tt)
        #pragma unroll
        for (int db = 0; db < 2; ++db)
            #pragma unroll
            for (int j = 0; j < 8; ++j)
                #pragma unroll
                for (int g = 0; g < 3; ++g) acc[tt][db][j][g] = 0.0f;

    for (int k0c = 0; k0c < 512; k0c += 32) {
        {
            const int p = tid & 15, bg = tid >> 4;
            #pragma unroll
            for (int tt = 0; tt < 2; ++tt)
                #pragma unroll
                for (int j = 0; j < 2; ++j) {
                    const int bb = bg * 2 + j;
                    const float2 v = *(const float2*)(word + (((size_t)(t0 + tt) * 32 + bb) * 512 + k0c + 2 * p));
                    xs2[tt][p][bb] = pack2h(v.x, v.y);
                }
        }
        {
            #pragma unroll
            for (int cc = 0; cc < 6; ++cc) {
                const int c = tid + 256 * cc;
                const int g = c >> 9, r = c & 511, pg = r >> 7, i = r & 127;
                const float* src = Wg[g] + (size_t)(d0 + i) * 512 + k0c + 8 * pg;
                const float4 v0 = ((const float4*)src)[0];
                const float4 v1 = ((const float4*)src)[1];
                uint4 cell;
                cell.x = pack2h(v0.x, v0.y); cell.y = pack2h(v0.z, v0.w);
                cell.z = pack2h(v1.x, v1.y); cell.w = pack2h(v1.z, v1.w);
                ws2v[g][i][(pg + (i >> 2)) & 3] = cell;
            }
        }
        __syncthreads();
        #pragma unroll
        for (int pg = 0; pg < 4; ++pg) {
            uint4 wc[3][2];
            #pragma unroll
            for (int g = 0; g < 3; ++g)
                #pragma unroll
                for (int db = 0; db < 2; ++db) {
                    const int d = d_l + 64 * db;
                    wc[g][db] = ws2v[g][d][(pg + (d >> 2)) & 3];
                }
            #pragma unroll
            for (int p = 0; p < 4; ++p) {
                const int pair = 4 * pg + p;
                u32 x2[2][8];
                #pragma unroll
                for (int tt = 0; tt < 2; ++tt) {
                    const uint4* xr = (const uint4*)&xs2[tt][pair][bq * 8];
                    uint4 xa = xr[0], xb = xr[1];
                    x2[tt][0] = xa.x; x2[tt][1] = xa.y; x2[tt][2] = xa.z; x2[tt][3] = xa.w;
                    x2[tt][4] = xb.x; x2[tt][5] = xb.y; x2[tt][6] = xb.z; x2[tt][7] = xb.w;
                }
                u32 w[3][2];
                #pragma unroll
                for (int g = 0; g < 3; ++g)
                    #pragma unroll
                    for (int db = 0; db < 2; ++db) {
                        const uint4 v = wc[g][db];
                        w[g][db] = (p == 0) ? v.x : (p == 1) ? v.y : (p == 2) ? v.z : v.w;
                    }
                #pragma unroll
                for (int tt = 0; tt < 2; ++tt)
                    #pragma unroll
                    for (int db = 0; db < 2; ++db)
                        #pragma unroll
                        for (int j = 0; j < 8; ++j)
                            #pragma unroll
                            for (int g = 0; g < 3; ++g)
                                acc[tt][db][j][g] = fdot2(x2[tt][j], w[g][db], acc[tt][db][j][g]);
            }
        }
        __syncthreads();
    }

    #pragma unroll
    for (int db = 0; db < 2; ++db) {
        const int d = d0 + 64 * db + d_l;
        const float b0 = 2.0f * bi[d];
        const float b1 = bz[d] + bi[d];
        const float b2 = bo[d] + bi[d];
        #pragma unroll
        for (int tt = 0; tt < 2; ++tt)
            #pragma unroll
            for (int j = 0; j < 8; ++j) {
                const size_t o = ((size_t)(t0 + tt) * 32 + (bq * 8 + j)) * 512 + d;
                Xi[o] = f2h(acc[tt][db][j][0] + b0);
                Xz[o] = f2h(acc[tt][db][j][1] + b1);
                Xo[o] = f2h(acc[tt][db][j][2] + b2);
            }
    }
}

// ---------------------------------------------------------------------------
// K2 v9b: identical design to v9; compile fix only. The "+v" asm pin is legal
// on clang ext_vector types (v7/v8's u32x16 compiled) but NOT on HIP's uint4
// struct ("tied indirect register inputs"). VGPR-resident weight quads are
// now u32x4 ext-vectors; LDS rows stay uint4 (no pins needed there).
// Design recap: packed W is 512 KB = 100% of the CU register file, so full
// VGPR residency is impossible. 256-thread WG (1 wave/SIMD -> 512-VGPR cap).
// Thread (dg=tid>>3, ks=tid&7): 16 output rows over a 32-pair K-slice;
// rows 0..12 in VGPRs (104 pinned u32x4 = 416 regs), rows 13..15 in LDS
// (96 KB, chunk-major, conflict-free b128). h ping-pong at 72-u16 stride.
// Two 3-stage shfl_xor butterflies -> thread owns d0=16dg+ks, d1=d0+8.
// One barrier/step. Demand ~470 of 512 -> no forced spill.
// ---------------------------------------------------------------------------
#define PINV(x) asm volatile("" : "+v"(x));

#define ROW(r) \
    const u32x4* wp##r = (const u32x4*)(WpkT + ((size_t)(16 * dg + r) * 256 + 32 * ks)); \
    u32x4 W##r##0 = wp##r[0], W##r##1 = wp##r[1], W##r##2 = wp##r[2], W##r##3 = wp##r[3], \
          W##r##4 = wp##r[4], W##r##5 = wp##r[5], W##r##6 = wp##r[6], W##r##7 = wp##r[7]; \
    PINV(W##r##0) PINV(W##r##1) PINV(W##r##2) PINV(W##r##3) \
    PINV(W##r##4) PINV(W##r##5) PINV(W##r##6) PINV(W##r##7)

#define DOT4(A, hc, wv) \
    A = fdot2(hc.x, (wv).x, A); A = fdot2(hc.y, (wv).y, A); \
    A = fdot2(hc.z, (wv).z, A); A = fdot2(hc.w, (wv).w, A);

#define CCBLK(cc) { \
    const uint4 hc   = hv[cc]; \
    const uint4 wl13 = wl[0 * 8 + cc][tid]; \
    const uint4 wl14 = wl[1 * 8 + cc][tid]; \
    const uint4 wl15 = wl[2 * 8 + cc][tid]; \
    DOT4(a0,  hc, W0##cc)  DOT4(a1,  hc, W1##cc)  DOT4(a2,  hc, W2##cc) \
    DOT4(a3,  hc, W3##cc)  DOT4(a4,  hc, W4##cc)  DOT4(a5,  hc, W5##cc) \
    DOT4(a6,  hc, W6##cc)  DOT4(a7,  hc, W7##cc)  DOT4(a8,  hc, W8##cc) \
    DOT4(a9,  hc, W9##cc)  DOT4(a10, hc, W10##cc) DOT4(a11, hc, W11##cc) \
    DOT4(a12, hc, W12##cc) \
    DOT4(a13, hc, wl13)    DOT4(a14, hc, wl14)    DOT4(a15, hc, wl15) }

#define HSTR 72   // u16 stride per 64-element h slice (144 B; v7-proven, 0 conflicts)

__global__ __launch_bounds__(256)
__attribute__((amdgpu_waves_per_eu(1, 1)))
void k2_recur(
    const u16* __restrict__ Xi, const u16* __restrict__ Xz, const u16* __restrict__ Xo,
    const u32* __restrict__ WpkT, const u32* __restrict__ Wypk,
    const float* __restrict__ by, float* __restrict__ out)
{
    __shared__ uint4 wl[24][256];                 // 96 KB: LDS-resident rows 13..15
    __shared__ alignas(16) u16 hb[2][8 * HSTR];   // strided h, f16, ping-pong

    const int b   = blockIdx.x;                   // 0..31
    const int tid = threadIdx.x;
    const int dg  = tid >> 3;                     // output group (16 rows)
    const int ks  = tid & 7;                      // K-slice (32 pairs)

    // VGPR-resident weight rows 0..12 (named ext-vector SSA + opaque pins)
    ROW(0)  ROW(1)  ROW(2)  ROW(3)  ROW(4)  ROW(5)  ROW(6)
    ROW(7)  ROW(8)  ROW(9)  ROW(10) ROW(11) ROW(12)

    // stage LDS-resident rows 13..15: wl[(r-13)*8+cc][tid]
    #pragma unroll
    for (int rr = 0; rr < 3; ++rr) {
        const uint4* src = (const uint4*)(WpkT + ((size_t)(16 * dg + 13 + rr) * 256 + 32 * ks));
        #pragma unroll
        for (int cc = 0; cc < 8; ++cc) wl[rr * 8 + cc][tid] = src[cc];
    }

    // h = 0 at t = 0 (zero full strided buffer)
    hb[0][tid] = (u16)0;
    hb[0][tid + 256] = (u16)0;
    if (tid < 8 * HSTR - 512) hb[0][tid + 512] = (u16)0;
    __syncthreads();

    const int d0 = 16 * dg + ks;                  // outputs owned after butterfly
    const int d1 = d0 + 8;

    u16 xi0 = Xi[(size_t)b * 512 + d0], xz0 = Xz[(size_t)b * 512 + d0], xo0 = Xo[(size_t)b * 512 + d0];
    u16 xi1 = Xi[(size_t)b * 512 + d1], xz1 = Xz[(size_t)b * 512 + d1], xo1 = Xo[(size_t)b * 512 + d1];

    const int hw0 = (d0 >> 6) * HSTR + (d0 & 63);
    const int hw1 = (d1 >> 6) * HSTR + (d1 & 63);
    const int sb0 = tid & 1, sb1 = tid & 2, sb2 = tid & 4;

    for (int t = 0; t < 2048; ++t) {
        const int par = t & 1;

        // prefetch next-step x (hides under the dot)
        const int tn = (t + 1) & 2047;
        const size_t xb = ((size_t)tn * 32 + b) * 512;
        const u16 xi0n = Xi[xb + d0], xz0n = Xz[xb + d0], xo0n = Xo[xb + d0];
        const u16 xi1n = Xi[xb + d1], xz1n = Xz[xb + d1], xo1n = Xo[xb + d1];

        // 16 partial dots over this thread's 32-pair K-slice
        const uint4* hv = (const uint4*)((const char*)&hb[par][0] + ks * 144);
        float a0 = 0.f, a1 = 0.f, a2 = 0.f, a3 = 0.f, a4 = 0.f, a5 = 0.f,
              a6 = 0.f, a7 = 0.f, a8 = 0.f, a9 = 0.f, a10 = 0.f, a11 = 0.f,
              a12 = 0.f, a13 = 0.f, a14 = 0.f, a15 = 0.f;
        CCBLK(0) CCBLK(1) CCBLK(2) CCBLK(3)
        CCBLK(4) CCBLK(5) CCBLK(6) CCBLK(7)

        // butterfly A (rows 0..7): lane ks ends with row 16dg+ks == d0
        float vA, vB;
        {
            float s, k, q0, q1, q2, q3, r0, r1;
            s = sb0 ? a0 : a1; k = sb0 ? a1 : a0; q0 = k + __shfl_xor(s, 1);
            s = sb0 ? a2 : a3; k = sb0 ? a3 : a2; q1 = k + __shfl_xor(s, 1);
            s = sb0 ? a4 : a5; k = sb0 ? a5 : a4; q2 = k + __shfl_xor(s, 1);
            s = sb0 ? a6 : a7; k = sb0 ? a7 : a6; q3 = k + __shfl_xor(s, 1);
            s = sb1 ? q0 : q1; k = sb1 ? q1 : q0; r0 = k + __shfl_xor(s, 2);
            s = sb1 ? q2 : q3; k = sb1 ? q3 : q2; r1 = k + __shfl_xor(s, 2);
            s = sb2 ? r0 : r1; k = sb2 ? r1 : r0; vA = k + __shfl_xor(s, 4);
        }
        // butterfly B (rows 8..15): lane ks ends with row 16dg+8+ks == d1
        {
            float s, k, q0, q1, q2, q3, r0, r1;
            s = sb0 ? a8  : a9;  k = sb0 ? a9  : a8;  q0 = k + __shfl_xor(s, 1);
            s = sb0 ? a10 : a11; k = sb0 ? a11 : a10; q1 = k + __shfl_xor(s, 1);
            s = sb0 ? a12 : a13; k = sb0 ? a13 : a12; q2 = k + __shfl_xor(s, 1);
            s = sb0 ? a14 : a15; k = sb0 ? a15 : a14; q3 = k + __shfl_xor(s, 1);
            s = sb1 ? q0 : q1; k = sb1 ? q1 : q0; r0 = k + __shfl_xor(s, 2);
            s = sb1 ? q2 : q3; k = sb1 ? q3 : q2; r1 = k + __shfl_xor(s, 2);
            s = sb2 ? r0 : r1; k = sb2 ? r1 : r0; vB = k + __shfl_xor(s, 4);
        }

        // gates for both owned outputs
        {
            const float zi = fsigmoid(h2f(xi0) + vA);
            const float z  = fsigmoid(h2f(xz0) + vA);
            const float zo = fsigmoid(h2f(xo0) + vA);
            hb[par ^ 1][hw0] = f2h(zo * ftanh_pos(zi * z));
        }
        {
            const float zi = fsigmoid(h2f(xi1) + vB);
            const float z  = fsigmoid(h2f(xz1) + vB);
            const float zo = fsigmoid(h2f(xo1) + vB);
            hb[par ^ 1][hw1] = f2h(zo * ftanh_pos(zi * z));
        }
        __syncthreads();                     // single barrier per step

        xi0 = xi0n; xz0 = xz0n; xo0 = xo0n;
        xi1 = xi1n; xz1 = xz1n; xo1 = xo1n;
    }

    // epilogue: final h is in hb[0] (t=2047, par=1 wrote hb[0]).
    // Same per-output accumulation order as v7.
    #pragma unroll
    for (int u = 0; u < 2; ++u) {
        const int d = d0 + 8 * u;
        float e0 = 0.f, e1 = 0.f, e2 = 0.f, e3 = 0.f;
        #pragma unroll
        for (int s = 0; s < 8; ++s) {
            const uint4* hv0 = (const uint4*)((const char*)&hb[0][0] + s * 144);
            #pragma unroll
            for (int c = 0; c < 8; ++c) {
                const uint4 hc = hv0[c];
                const int i = 8 * s + c;
                e0 = fdot2(hc.x, Wypk[(size_t)(4 * i + 0) * 512 + d], e0);
                e1 = fdot2(hc.y, Wypk[(size_t)(4 * i + 1) * 512 + d], e1);
                e2 = fdot2(hc.z, Wypk[(size_t)(4 * i + 2) * 512 + d], e2);
                e3 = fdot2(hc.w, Wypk[(size_t)(4 * i + 3) * 512 + d], e3);
            }
        }
        out[(size_t)b * 512 + d] = (e0 + e1) + (e2 + e3) + by[d];
    }
}

// ---------------------------------------------------------------------------
extern "C" void kernel_launch(void* const* d_in, const int* in_sizes, int n_in,
                              void* d_out, int out_size, void* d_ws, size_t ws_size,
                              hipStream_t stream) {
    const float* word = (const float*)d_in[0];
    // d_in[1]=Wf, d_in[2]=bf : dead in the reference (c==0 path), unused.
    const float* Wi = (const float*)d_in[3];
    const float* bi = (const float*)d_in[4];
    const float* Wz = (const float*)d_in[5];
    const float* bz = (const float*)d_in[6];
    const float* Wo = (const float*)d_in[7];
    const float* bo = (const float*)d_in[8];
    const float* Wy = (const float*)d_in[9];
    const float* by = (const float*)d_in[10];
    float* out = (float*)d_out;

    char* ws = (char*)d_ws;
    const size_t XN = (size_t)2048 * 32 * 512 * sizeof(u16);  // 64 MB per gate array
    u16* Xi = (u16*)(ws);
    u16* Xz = (u16*)(ws + XN);
    u16* Xo = (u16*)(ws + 2 * XN);
    u32* WpkT = (u32*)(ws + 3 * XN);                          // 512 KB
    u32* Wypk = (u32*)(ws + 3 * XN + (size_t)524288);         // 512 KB

    k0_pack<<<768, 256, 0, stream>>>(Wi, Wy, WpkT, Wypk);

    dim3 g1(1024, 4);
    k1_gates<<<g1, 256, 0, stream>>>(word, Wi, Wz, Wo, bi, bz, bo, Xi, Xz, Xo);

    k2_recur<<<32, 256, 0, stream>>>(Xi, Xz, Xo, WpkT, Wypk, by, out);
}

// Round 7
// 4274.458 us; speedup vs baseline: 2.2839x; 1.4417x over previous
//
#include <hip/hip_runtime.h>

typedef unsigned int u32;
typedef unsigned short u16;
typedef unsigned long long u64;
typedef _Float16 f16;
typedef f16 f16x2 __attribute__((ext_vector_type(2)));
typedef u32 u32x4 __attribute__((ext_vector_type(4)));   // asm-pinnable quad

__device__ __forceinline__ float fdot2(u32 a, u32 b, float c) {
#if __has_builtin(__builtin_amdgcn_fdot2)
    return __builtin_amdgcn_fdot2(__builtin_bit_cast(f16x2, a),
                                  __builtin_bit_cast(f16x2, b), c, false);
#else
    f16x2 av = __builtin_bit_cast(f16x2, a), bv = __builtin_bit_cast(f16x2, b);
    c += (float)av[0] * (float)bv[0];
    c += (float)av[1] * (float)bv[1];
    return c;
#endif
}

__device__ __forceinline__ u32 pack2h(float a, float b) {
    f16x2 h; h[0] = (f16)a; h[1] = (f16)b;
    return __builtin_bit_cast(u32, h);
}
__device__ __forceinline__ float h2f(u16 x) { return (float)__builtin_bit_cast(f16, x); }
__device__ __forceinline__ u16 f2h(float x) { f16 h = (f16)x; return __builtin_bit_cast(u16, h); }

__device__ __forceinline__ float fexp(float x) {
#if __has_builtin(__builtin_amdgcn_exp2f)
    return __builtin_amdgcn_exp2f(x * 1.44269504088896f);
#else
    return __expf(x);
#endif
}
__device__ __forceinline__ float frcp(float x) {
#if __has_builtin(__builtin_amdgcn_rcpf)
    return __builtin_amdgcn_rcpf(x);
#else
    return 1.0f / x;
#endif
}
__device__ __forceinline__ float fsigmoid(float x) { return frcp(1.0f + fexp(-x)); }
__device__ __forceinline__ float ftanh_pos(float x) { return 1.0f - 2.0f * frcp(fexp(2.0f * x) + 1.0f); }

// ---------------------------------------------------------------------------
// K0: pack weights to f16 pairs. (unchanged)
//   WpkT[d][p] = (Wi[d][2p], Wi[d][2p+1])   d<512, p<256   (row-major rows)
//   Wypk[p][d] = (Wy[d][2p], Wy[d][2p+1])   (K2 epilogue layout)
// ---------------------------------------------------------------------------
__global__ __launch_bounds__(256) void k0_pack(const float* __restrict__ Wi,
                                               const float* __restrict__ Wy,
                                               u32* __restrict__ WpkT,
                                               u32* __restrict__ Wypk) {
    const int bx = blockIdx.x, tid = threadIdx.x;
    if (bx < 512) {
        const float2 v = *(const float2*)(Wi + (size_t)bx * 512 + 2 * tid);
        WpkT[(size_t)bx * 256 + tid] = pack2h(v.x, v.y);
    } else {
        const int p = bx - 512;
        #pragma unroll
        for (int r = 0; r < 2; ++r) {
            const int d = tid + 256 * r;
            Wypk[(size_t)p * 512 + d] =
                pack2h(Wy[(size_t)d * 512 + 2 * p], Wy[(size_t)d * 512 + 2 * p + 1]);
        }
    }
}

// ---------------------------------------------------------------------------
// K1: gate pre-activations (parallel over all t). Unchanged.
// ---------------------------------------------------------------------------
__global__ __launch_bounds__(256) void k1_gates(
    const float* __restrict__ word,
    const float* __restrict__ Wi, const float* __restrict__ Wz, const float* __restrict__ Wo,
    const float* __restrict__ bi, const float* __restrict__ bz, const float* __restrict__ bo,
    u16* __restrict__ Xi, u16* __restrict__ Xz, u16* __restrict__ Xo)
{
    __shared__ uint4 ws2v[3][128][4];
    __shared__ u32 xs2[2][16][36];

    const int tid = threadIdx.x;
    const int d_l = tid & 63;
    const int bq  = tid >> 6;
    const int t0  = blockIdx.x * 2;
    const int d0  = blockIdx.y * 128;

    const float* Wg[3] = {Wi, Wz, Wo};

    float acc[2][2][8][3];
    #pragma unroll
    for (int tt = 0; tt < 2; ++tt)
        #pragma unroll
        for (int db = 0; db < 2; ++db)
            #pragma unroll
            for (int j = 0; j < 8; ++j)
                #pragma unroll
                for (int g = 0; g < 3; ++g) acc[tt][db][j][g] = 0.0f;

    for (int k0c = 0; k0c < 512; k0c += 32) {
        {
            const int p = tid & 15, bg = tid >> 4;
            #pragma unroll
            for (int tt = 0; tt < 2; ++tt)
                #pragma unroll
                for (int j = 0; j < 2; ++j) {
                    const int bb = bg * 2 + j;
                    const float2 v = *(const float2*)(word + (((size_t)(t0 + tt) * 32 + bb) * 512 + k0c + 2 * p));
                    xs2[tt][p][bb] = pack2h(v.x, v.y);
                }
        }
        {
            #pragma unroll
            for (int cc = 0; cc < 6; ++cc) {
                const int c = tid + 256 * cc;
                const int g = c >> 9, r = c & 511, pg = r >> 7, i = r & 127;
                const float* src = Wg[g] + (size_t)(d0 + i) * 512 + k0c + 8 * pg;
                const float4 v0 = ((const float4*)src)[0];
                const float4 v1 = ((const float4*)src)[1];
                uint4 cell;
                cell.x = pack2h(v0.x, v0.y); cell.y = pack2h(v0.z, v0.w);
                cell.z = pack2h(v1.x, v1.y); cell.w = pack2h(v1.z, v1.w);
                ws2v[g][i][(pg + (i >> 2)) & 3] = cell;
            }
        }
        __syncthreads();
        #pragma unroll
        for (int pg = 0; pg < 4; ++pg) {
            uint4 wc[3][2];
            #pragma unroll
            for (int g = 0; g < 3; ++g)
                #pragma unroll
                for (int db = 0; db < 2; ++db) {
                    const int d = d_l + 64 * db;
                    wc[g][db] = ws2v[g][d][(pg + (d >> 2)) & 3];
                }
            #pragma unroll
            for (int p = 0; p < 4; ++p) {
                const int pair = 4 * pg + p;
                u32 x2[2][8];
                #pragma unroll
                for (int tt = 0; tt < 2; ++tt) {
                    const uint4* xr = (const uint4*)&xs2[tt][pair][bq * 8];
                    uint4 xa = xr[0], xb = xr[1];
                    x2[tt][0] = xa.x; x2[tt][1] = xa.y; x2[tt][2] = xa.z; x2[tt][3] = xa.w;
                    x2[tt][4] = xb.x; x2[tt][5] = xb.y; x2[tt][6] = xb.z; x2[tt][7] = xb.w;
                }
                u32 w[3][2];
                #pragma unroll
                for (int g = 0; g < 3; ++g)
                    #pragma unroll
                    for (int db = 0; db < 2; ++db) {
                        const uint4 v = wc[g][db];
                        w[g][db] = (p == 0) ? v.x : (p == 1) ? v.y : (p == 2) ? v.z : v.w;
                    }
                #pragma unroll
                for (int tt = 0; tt < 2; ++tt)
                    #pragma unroll
                    for (int db = 0; db < 2; ++db)
                        #pragma unroll
                        for (int j = 0; j < 8; ++j)
                            #pragma unroll
                            for (int g = 0; g < 3; ++g)
                                acc[tt][db][j][g] = fdot2(x2[tt][j], w[g][db], acc[tt][db][j][g]);
            }
        }
        __syncthreads();
    }

    #pragma unroll
    for (int db = 0; db < 2; ++db) {
        const int d = d0 + 64 * db + d_l;
        const float b0 = 2.0f * bi[d];
        const float b1 = bz[d] + bi[d];
        const float b2 = bo[d] + bi[d];
        #pragma unroll
        for (int tt = 0; tt < 2; ++tt)
            #pragma unroll
            for (int j = 0; j < 8; ++j) {
                const size_t o = ((size_t)(t0 + tt) * 32 + (bq * 8 + j)) * 512 + d;
                Xi[o] = f2h(acc[tt][db][j][0] + b0);
                Xz[o] = f2h(acc[tt][db][j][1] + b1);
                Xo[o] = f2h(acc[tt][db][j][2] + b2);
            }
    }
}

// ---------------------------------------------------------------------------
// K2 v10: feasible-residency, 512-thread WG (2 waves/SIMD).
// Post-mortem of v9b: VGPR_Count=256 = the ARCH cap per wave (the "512/wave"
// figure is the unified VGPR+AGPR total; plain VALU code addresses only 256).
// v9b's 416-u32 demand overflowed by ~200 -> AGPR/scratch shuffling (~63%
// per-CU VALUBusy, 5800 cy/step). v10 makes demand FIT:
// thread (dg=tid>>3 in 0..63, ks=tid&7): 8 rows {8dg..8dg+7} x 32 pairs.
// Rows 0..5 (192 u32 = 48 pinned u32x4) in VGPRs -> demand ~240 <= 256.
// Rows 6..7 in LDS (wl[16][512] uint4 = 128 KB, chunk-major, conflict-free).
// v7's proven single butterfly -> thread owns output d == tid. One gate,
// 3 x-loads per thread per step. 2 waves/SIMD give TLP to hide LDS latency.
// Expected: LDS-pipe-bound ~2300-2600 cy/step.
// ---------------------------------------------------------------------------
#define PINV(x) asm volatile("" : "+v"(x));

#define ROW(r) \
    const u32x4* wp##r = (const u32x4*)(WpkT + ((size_t)(8 * dg + r) * 256 + 32 * ks)); \
    u32x4 W##r##0 = wp##r[0], W##r##1 = wp##r[1], W##r##2 = wp##r[2], W##r##3 = wp##r[3], \
          W##r##4 = wp##r[4], W##r##5 = wp##r[5], W##r##6 = wp##r[6], W##r##7 = wp##r[7]; \
    PINV(W##r##0) PINV(W##r##1) PINV(W##r##2) PINV(W##r##3) \
    PINV(W##r##4) PINV(W##r##5) PINV(W##r##6) PINV(W##r##7)

#define DOT4(A, hc, wv) \
    A = fdot2(hc.x, (wv).x, A); A = fdot2(hc.y, (wv).y, A); \
    A = fdot2(hc.z, (wv).z, A); A = fdot2(hc.w, (wv).w, A);

#define CCBLK(cc) { \
    const uint4 hc  = hv[cc]; \
    const uint4 wl6 = wl[cc][tid]; \
    const uint4 wl7 = wl[8 + cc][tid]; \
    DOT4(a0, hc, W0##cc)  DOT4(a1, hc, W1##cc)  DOT4(a2, hc, W2##cc) \
    DOT4(a3, hc, W3##cc)  DOT4(a4, hc, W4##cc)  DOT4(a5, hc, W5##cc) \
    DOT4(a6, hc, wl6)     DOT4(a7, hc, wl7) }

#define HSTR 72   // u16 stride per 64-element h slice (144 B; v7-proven, 0 conflicts)

__global__ __launch_bounds__(512)
__attribute__((amdgpu_waves_per_eu(2, 2)))
void k2_recur(
    const u16* __restrict__ Xi, const u16* __restrict__ Xz, const u16* __restrict__ Xo,
    const u32* __restrict__ WpkT, const u32* __restrict__ Wypk,
    const float* __restrict__ by, float* __restrict__ out)
{
    __shared__ uint4 wl[16][512];                 // 128 KB: LDS-resident rows 6..7
    __shared__ alignas(16) u16 hb[2][8 * HSTR];   // strided h, f16, ping-pong

    const int b   = blockIdx.x;                   // 0..31
    const int tid = threadIdx.x;
    const int dg  = tid >> 3;                     // output group (8 rows), 0..63
    const int ks  = tid & 7;                      // K-slice (32 pairs)

    // VGPR-resident weight rows 0..5 (named ext-vector SSA + opaque pins)
    ROW(0) ROW(1) ROW(2) ROW(3) ROW(4) ROW(5)

    // stage LDS-resident rows 6..7: wl[rr*8+cc][tid]
    #pragma unroll
    for (int rr = 0; rr < 2; ++rr) {
        const uint4* src = (const uint4*)(WpkT + ((size_t)(8 * dg + 6 + rr) * 256 + 32 * ks));
        #pragma unroll
        for (int cc = 0; cc < 8; ++cc) wl[rr * 8 + cc][tid] = src[cc];
    }

    // h = 0 at t = 0 (zero both ping-pong buffers incl. pads)
    for (int i = tid; i < 2 * 8 * HSTR; i += 512) ((u16*)hb)[i] = (u16)0;
    __syncthreads();

    // this thread owns output d == tid after the butterfly
    u16 xi_c = Xi[(size_t)b * 512 + tid];
    u16 xz_c = Xz[(size_t)b * 512 + tid];
    u16 xo_c = Xo[(size_t)b * 512 + tid];

    const int hwr = (tid >> 6) * HSTR + (tid & 63);   // strided publish slot
    const int sb0 = tid & 1, sb1 = tid & 2, sb2 = tid & 4;

    for (int t = 0; t < 2048; ++t) {
        const int par = t & 1;

        // prefetch next-step x (latency hides under the dot)
        const int tn = (t + 1) & 2047;
        const size_t xb = ((size_t)tn * 32 + b) * 512 + tid;
        const u16 xi_n = Xi[xb], xz_n = Xz[xb], xo_n = Xo[xb];

        // 8 partial dots over this thread's 32-pair K-slice
        const uint4* hv = (const uint4*)((const char*)&hb[par][0] + ks * 144);
        float a0 = 0.f, a1 = 0.f, a2 = 0.f, a3 = 0.f,
              a4 = 0.f, a5 = 0.f, a6 = 0.f, a7 = 0.f;
        CCBLK(0) CCBLK(1) CCBLK(2) CCBLK(3)
        CCBLK(4) CCBLK(5) CCBLK(6) CCBLK(7)

        // 3-stage in-wave butterfly over the 8-lane group (v7-proven):
        // lane ks ends with the full dot for output 8dg+ks == tid.
        float q0, q1, q2, q3;
        {
            float s, k;
            s = sb0 ? a0 : a1; k = sb0 ? a1 : a0; q0 = k + __shfl_xor(s, 1);
            s = sb0 ? a2 : a3; k = sb0 ? a3 : a2; q1 = k + __shfl_xor(s, 1);
            s = sb0 ? a4 : a5; k = sb0 ? a5 : a4; q2 = k + __shfl_xor(s, 1);
            s = sb0 ? a6 : a7; k = sb0 ? a7 : a6; q3 = k + __shfl_xor(s, 1);
        }
        float r0, r1;
        {
            float s, k;
            s = sb1 ? q0 : q1; k = sb1 ? q1 : q0; r0 = k + __shfl_xor(s, 2);
            s = sb1 ? q2 : q3; k = sb1 ? q3 : q2; r1 = k + __shfl_xor(s, 2);
        }
        float v;
        {
            float s = sb2 ? r0 : r1, k = sb2 ? r1 : r0;
            v = k + __shfl_xor(s, 4);
        }

        const float zi = fsigmoid(h2f(xi_c) + v);
        const float z  = fsigmoid(h2f(xz_c) + v);
        const float zo = fsigmoid(h2f(xo_c) + v);
        const float hn = zo * ftanh_pos(zi * z);

        hb[par ^ 1][hwr] = f2h(hn);          // publish h for step t+1
        __syncthreads();                     // single barrier per step

        xi_c = xi_n; xz_c = xz_n; xo_c = xo_n;
    }

    // epilogue: final h is in hb[0] (t=2047, par=1 wrote hb[0]).
    // Same accumulation order as v7/v9b (global chunk i = 8s+c ascending).
    {
        float e0 = 0.f, e1 = 0.f, e2 = 0.f, e3 = 0.f;
        #pragma unroll
        for (int s = 0; s < 8; ++s) {
            const uint4* hv0 = (const uint4*)((const char*)&hb[0][0] + s * 144);
            #pragma unroll
            for (int c = 0; c < 8; ++c) {
                const uint4 hc = hv0[c];
                const int i = 8 * s + c;
                e0 = fdot2(hc.x, Wypk[(size_t)(4 * i + 0) * 512 + tid], e0);
                e1 = fdot2(hc.y, Wypk[(size_t)(4 * i + 1) * 512 + tid], e1);
                e2 = fdot2(hc.z, Wypk[(size_t)(4 * i + 2) * 512 + tid], e2);
                e3 = fdot2(hc.w, Wypk[(size_t)(4 * i + 3) * 512 + tid], e3);
            }
        }
        out[(size_t)b * 512 + tid] = (e0 + e1) + (e2 + e3) + by[tid];
    }
}

// ---------------------------------------------------------------------------
extern "C" void kernel_launch(void* const* d_in, const int* in_sizes, int n_in,
                              void* d_out, int out_size, void* d_ws, size_t ws_size,
                              hipStream_t stream) {
    const float* word = (const float*)d_in[0];
    // d_in[1]=Wf, d_in[2]=bf : dead in the reference (c==0 path), unused.
    const float* Wi = (const float*)d_in[3];
    const float* bi = (const float*)d_in[4];
    const float* Wz = (const float*)d_in[5];
    const float* bz = (const float*)d_in[6];
    const float* Wo = (const float*)d_in[7];
    const float* bo = (const float*)d_in[8];
    const float* Wy = (const float*)d_in[9];
    const float* by = (const float*)d_in[10];
    float* out = (float*)d_out;

    char* ws = (char*)d_ws;
    const size_t XN = (size_t)2048 * 32 * 512 * sizeof(u16);  // 64 MB per gate array
    u16* Xi = (u16*)(ws);
    u16* Xz = (u16*)(ws + XN);
    u16* Xo = (u16*)(ws + 2 * XN);
    u32* WpkT = (u32*)(ws + 3 * XN);                          // 512 KB
    u32* Wypk = (u32*)(ws + 3 * XN + (size_t)524288);         // 512 KB

    k0_pack<<<768, 256, 0, stream>>>(Wi, Wy, WpkT, Wypk);

    dim3 g1(1024, 4);
    k1_gates<<<g1, 256, 0, stream>>>(word, Wi, Wz, Wo, bi, bz, bo, Xi, Xz, Xo);

    k2_recur<<<32, 512, 0, stream>>>(Xi, Xz, Xo, WpkT, Wypk, by, out);
}